// Round 1
// baseline (1948.653 us; speedup 1.0000x reference)
//
#include <hip/hip_runtime.h>
#include <hip/hip_bf16.h>

// ---------------- constants (problem shape) ----------------
// B=2, S=2048, H=2048, NH=16, LD=512, HD=128
#define PB   2
#define PS   2048
#define PH   2048
#define PNH  16
#define PLD  512
#define PHD  128
#define PM   (PB * PS)          // 4096 rows in all GEMMs
#define ATT_SCALE 0.08838834764831845f  // 1/sqrt(128)

typedef __attribute__((ext_vector_type(8))) short bf16x8;
typedef __attribute__((ext_vector_type(4))) float f32x4;

__device__ __forceinline__ float bf2f(unsigned int h) {
    return __uint_as_float(h << 16);
}
__device__ __forceinline__ unsigned short f2bf(float f) {
    unsigned int u = __float_as_uint(f);
    u += 0x7FFFu + ((u >> 16) & 1u);   // RNE
    return (unsigned short)(u >> 16);
}

// ---------------- cast fp32 -> bf16 (elementwise, 4/thread) ----------------
__global__ __launch_bounds__(256) void cast_f32_bf16_kernel(
    const float* __restrict__ in, unsigned short* __restrict__ out, int n)
{
    int i = (blockIdx.x * 256 + threadIdx.x) * 4;
    if (i >= n) return;
    float4 f = *(const float4*)(in + i);
    unsigned int a = (unsigned int)f2bf(f.x) | ((unsigned int)f2bf(f.y) << 16);
    unsigned int b = (unsigned int)f2bf(f.z) | ((unsigned int)f2bf(f.w) << 16);
    *(uint2*)(out + i) = make_uint2(a, b);
}

// ---------------- transpose + cast: in fp32 [R][C] -> out bf16 [C][R] ----------------
__global__ __launch_bounds__(256) void transpose_cast_kernel(
    const float* __restrict__ in, unsigned short* __restrict__ out, int R, int C)
{
    __shared__ float tile[32][33];
    int tx = threadIdx.x, ty = threadIdx.y;
    int r0 = blockIdx.y * 32, c0 = blockIdx.x * 32;
#pragma unroll
    for (int i = 0; i < 32; i += 8)
        tile[ty + i][tx] = in[(size_t)(r0 + ty + i) * C + (c0 + tx)];
    __syncthreads();
#pragma unroll
    for (int i = 0; i < 32; i += 8)
        out[(size_t)(c0 + ty + i) * R + (r0 + tx)] = f2bf(tile[tx][ty + i]);
}

// ---------------- bf16 MFMA GEMM: C[M][N] = A[M][K] @ B[K][N] (+bias) ----------------
// A bf16 row-major [M][K]; BT bf16 row-major [N][K] (i.e. B transposed).
// grid (N/64, M/64), block 256 (4 waves, 2x2 of 32x32 per wave -> 2x2 of 16x16x32 MFMA).
template<bool BF16_OUT, bool HAS_BIAS>
__global__ __launch_bounds__(256) void gemm_bt_kernel(
    const unsigned short* __restrict__ A,
    const unsigned short* __restrict__ BT,
    const float* __restrict__ bias,
    void* __restrict__ Cout,
    int M, int N, int K)
{
    __shared__ __align__(16) unsigned short As[64 * 32];
    __shared__ __align__(16) unsigned short Bs[64 * 32];

    const int tid  = threadIdx.x;
    const int wave = tid >> 6;
    const int lane = tid & 63;
    const int wm = wave >> 1, wn = wave & 1;
    const int quad = lane >> 4, l15 = lane & 15;
    const int bm = blockIdx.y * 64, bn = blockIdx.x * 64;

    f32x4 acc[2][2] = {};

    const int lr = tid >> 2;          // 0..63 staging row
    const int lc = (tid & 3) * 8;     // 0,8,16,24 staging col
    const unsigned short* aptr = A  + (size_t)(bm + lr) * K + lc;
    const unsigned short* bptr = BT + (size_t)(bn + lr) * K + lc;

    for (int k0 = 0; k0 < K; k0 += 32) {
        *(bf16x8*)&As[lr * 32 + lc] = *(const bf16x8*)(aptr + k0);
        *(bf16x8*)&Bs[lr * 32 + lc] = *(const bf16x8*)(bptr + k0);
        __syncthreads();
        bf16x8 a0 = *(const bf16x8*)&As[(wm * 32 +      l15) * 32 + quad * 8];
        bf16x8 a1 = *(const bf16x8*)&As[(wm * 32 + 16 + l15) * 32 + quad * 8];
        bf16x8 b0 = *(const bf16x8*)&Bs[(wn * 32 +      l15) * 32 + quad * 8];
        bf16x8 b1 = *(const bf16x8*)&Bs[(wn * 32 + 16 + l15) * 32 + quad * 8];
        acc[0][0] = __builtin_amdgcn_mfma_f32_16x16x32_bf16(a0, b0, acc[0][0], 0, 0, 0);
        acc[0][1] = __builtin_amdgcn_mfma_f32_16x16x32_bf16(a0, b1, acc[0][1], 0, 0, 0);
        acc[1][0] = __builtin_amdgcn_mfma_f32_16x16x32_bf16(a1, b0, acc[1][0], 0, 0, 0);
        acc[1][1] = __builtin_amdgcn_mfma_f32_16x16x32_bf16(a1, b1, acc[1][1], 0, 0, 0);
        __syncthreads();
    }

#pragma unroll
    for (int mi = 0; mi < 2; ++mi)
#pragma unroll
        for (int ni = 0; ni < 2; ++ni)
#pragma unroll
            for (int r = 0; r < 4; ++r) {
                int row = bm + wm * 32 + mi * 16 + quad * 4 + r;  // C/D: row=quad*4+reg
                int col = bn + wn * 32 + ni * 16 + l15;           //      col=lane&15
                float val = acc[mi][ni][r];
                if (HAS_BIAS) val += bias[col];
                if (BF16_OUT)
                    ((unsigned short*)Cout)[(size_t)row * N + col] = f2bf(val);
                else
                    ((float*)Cout)[(size_t)row * N + col] = val;
            }
}

// ---------------- fp32 flash attention (bf16 q/k/v in, bf16 out) ----------------
// grid: B*NH*(S/16) blocks; block 256. 16 queries x 64-key tiles, online softmax.
__global__ __launch_bounds__(256) void flash_attn_kernel(
    const unsigned short* __restrict__ q,
    const unsigned short* __restrict__ k,
    const unsigned short* __restrict__ v,
    unsigned short* __restrict__ o)
{
    constexpr int QT = 16, KT = 64, HD = PHD, S = PS, H = PH;
    const int bid = blockIdx.x;
    const int qt = bid & ((S / QT) - 1);     // 0..127
    const int h  = (bid >> 7) & (PNH - 1);   // 0..15
    const int b  = bid >> 11;                // 0..1
    const int q0 = qt * QT;

    __shared__ __align__(16) float Qs[QT][HD];                 // fp32, pre-scaled
    __shared__ __align__(16) unsigned short Ks[KT][HD + 2];    // stride 130 (bank-skew)
    __shared__ __align__(16) unsigned short Vs[KT][HD + 8];    // stride 136 (16B aligned rows)
    __shared__ __align__(16) float Ss[QT][KT];
    __shared__ float mrow[QT], lrow[QT], arow[QT];

    const int t = threadIdx.x;

    // load+scale Q tile
    {
        int qi = t >> 4, d0 = (t & 15) * 8;
        uint4 u = *(const uint4*)(q + (size_t)(b * S + q0 + qi) * H + h * HD + d0);
        Qs[qi][d0 + 0] = bf2f(u.x & 0xFFFFu) * ATT_SCALE;
        Qs[qi][d0 + 1] = bf2f(u.x >> 16)     * ATT_SCALE;
        Qs[qi][d0 + 2] = bf2f(u.y & 0xFFFFu) * ATT_SCALE;
        Qs[qi][d0 + 3] = bf2f(u.y >> 16)     * ATT_SCALE;
        Qs[qi][d0 + 4] = bf2f(u.z & 0xFFFFu) * ATT_SCALE;
        Qs[qi][d0 + 5] = bf2f(u.z >> 16)     * ATT_SCALE;
        Qs[qi][d0 + 6] = bf2f(u.w & 0xFFFFu) * ATT_SCALE;
        Qs[qi][d0 + 7] = bf2f(u.w >> 16)     * ATT_SCALE;
    }
    if (t < QT) { mrow[t] = -1e30f; lrow[t] = 0.0f; }

    float acc[8] = {0, 0, 0, 0, 0, 0, 0, 0};

    const int nkt = (q0 + QT - 1) / KT + 1;
    for (int kt = 0; kt < nkt; ++kt) {
        const int k0 = kt * KT;
        __syncthreads();   // protect Ks/Vs/Ss from prior-iter readers (and covers Q staging on iter 0)
        // stage K,V tiles (bf16)
        {
            int ki = t >> 2, c0 = (t & 3) * 32;
            const unsigned short* krow = k + (size_t)(b * S + k0 + ki) * H + h * HD + c0;
            const unsigned short* vrow = v + (size_t)(b * S + k0 + ki) * H + h * HD + c0;
#pragma unroll
            for (int j = 0; j < 4; ++j) {
                uint4 a = *(const uint4*)(krow + j * 8);
                unsigned int* kd = (unsigned int*)&Ks[ki][c0 + j * 8];
                kd[0] = a.x; kd[1] = a.y; kd[2] = a.z; kd[3] = a.w;
                *(uint4*)&Vs[ki][c0 + j * 8] = *(const uint4*)(vrow + j * 8);
            }
        }
        __syncthreads();
        // scores: thread -> key (t&63), 4 queries ((t>>6)*4 ..+3)
        {
            int ki = t & 63, qb = (t >> 6) * 4;
            float sc[4] = {0, 0, 0, 0};
#pragma unroll
            for (int dc = 0; dc < HD; dc += 8) {
                const unsigned int* kp = (const unsigned int*)&Ks[ki][dc];
                float kf[8];
#pragma unroll
                for (int j = 0; j < 4; ++j) {
                    unsigned int u = kp[j];
                    kf[2 * j]     = bf2f(u & 0xFFFFu);
                    kf[2 * j + 1] = bf2f(u >> 16);
                }
#pragma unroll
                for (int jq = 0; jq < 4; ++jq) {
                    float4 qlo = *(const float4*)&Qs[qb + jq][dc];
                    float4 qhi = *(const float4*)&Qs[qb + jq][dc + 4];
                    sc[jq] += qlo.x * kf[0] + qlo.y * kf[1] + qlo.z * kf[2] + qlo.w * kf[3]
                            + qhi.x * kf[4] + qhi.y * kf[5] + qhi.z * kf[6] + qhi.w * kf[7];
                }
            }
            int kg = k0 + ki;
#pragma unroll
            for (int jq = 0; jq < 4; ++jq)
                Ss[qb + jq][ki] = (kg <= q0 + qb + jq) ? sc[jq] : -1e30f;
        }
        __syncthreads();
        // online-softmax row update (16 threads)
        if (t < QT) {
            float m_old = mrow[t], mx = m_old;
#pragma unroll 8
            for (int i = 0; i < KT; ++i) mx = fmaxf(mx, Ss[t][i]);
            float alpha = __expf(m_old - mx);
            float l = lrow[t] * alpha;
#pragma unroll 8
            for (int i = 0; i < KT; ++i) {
                float p = __expf(Ss[t][i] - mx);
                Ss[t][i] = p;
                l += p;
            }
            mrow[t] = mx; lrow[t] = l; arow[t] = alpha;
        }
        __syncthreads();
        // PV: thread -> (query t>>4, 8 dims (t&15)*8)
        {
            int qi = t >> 4, d0 = (t & 15) * 8;
            float alpha = arow[qi];
#pragma unroll
            for (int j = 0; j < 8; ++j) acc[j] *= alpha;
#pragma unroll 8
            for (int i = 0; i < KT; ++i) {
                float p = Ss[qi][i];
                uint4 vv = *(const uint4*)&Vs[i][d0];
                acc[0] += p * bf2f(vv.x & 0xFFFFu);
                acc[1] += p * bf2f(vv.x >> 16);
                acc[2] += p * bf2f(vv.y & 0xFFFFu);
                acc[3] += p * bf2f(vv.y >> 16);
                acc[4] += p * bf2f(vv.z & 0xFFFFu);
                acc[5] += p * bf2f(vv.z >> 16);
                acc[6] += p * bf2f(vv.w & 0xFFFFu);
                acc[7] += p * bf2f(vv.w >> 16);
            }
        }
    }
    // epilogue: normalize, pack bf16, store
    {
        int qi = t >> 4, d0 = (t & 15) * 8;
        float inv = 1.0f / lrow[qi];
        unsigned int w0 = (unsigned int)f2bf(acc[0] * inv) | ((unsigned int)f2bf(acc[1] * inv) << 16);
        unsigned int w1 = (unsigned int)f2bf(acc[2] * inv) | ((unsigned int)f2bf(acc[3] * inv) << 16);
        unsigned int w2 = (unsigned int)f2bf(acc[4] * inv) | ((unsigned int)f2bf(acc[5] * inv) << 16);
        unsigned int w3 = (unsigned int)f2bf(acc[6] * inv) | ((unsigned int)f2bf(acc[7] * inv) << 16);
        *(uint4*)(o + (size_t)(b * S + q0 + qi) * H + h * HD + d0) = make_uint4(w0, w1, w2, w3);
    }
}

// ---------------- host launcher ----------------
extern "C" void kernel_launch(void* const* d_in, const int* in_sizes, int n_in,
                              void* d_out, int out_size, void* d_ws, size_t ws_size,
                              hipStream_t stream)
{
    const float* x      = (const float*)d_in[0];
    const float* wq     = (const float*)d_in[1];
    const float* bq     = (const float*)d_in[2];
    const float* wk_lat = (const float*)d_in[3];
    const float* wv_lat = (const float*)d_in[4];
    const float* wk     = (const float*)d_in[5];
    const float* wv     = (const float*)d_in[6];
    const float* wo     = (const float*)d_in[7];
    const float* bo     = (const float*)d_in[8];
    float* out = (float*)d_out;

    char* ws = (char*)d_ws;
    size_t off = 0;
    auto alloc = [&](size_t bytes) -> void* {
        void* p = ws + off;
        off += (bytes + 255) & ~(size_t)255;
        return p;
    };
    unsigned short* xb      = (unsigned short*)alloc((size_t)PM * PH * 2);
    unsigned short* wqT     = (unsigned short*)alloc((size_t)PH * PH * 2);
    unsigned short* wkLatT  = (unsigned short*)alloc((size_t)PLD * PH * 2);
    unsigned short* wvLatT  = (unsigned short*)alloc((size_t)PLD * PH * 2);
    unsigned short* wkT     = (unsigned short*)alloc((size_t)PH * PLD * 2);
    unsigned short* wvT     = (unsigned short*)alloc((size_t)PH * PLD * 2);
    unsigned short* woT     = (unsigned short*)alloc((size_t)PH * PH * 2);
    unsigned short* qb      = (unsigned short*)alloc((size_t)PM * PH * 2);
    unsigned short* klat    = (unsigned short*)alloc((size_t)PM * PLD * 2);
    unsigned short* vlat    = (unsigned short*)alloc((size_t)PM * PLD * 2);
    unsigned short* kb      = (unsigned short*)alloc((size_t)PM * PH * 2);
    unsigned short* vb      = (unsigned short*)alloc((size_t)PM * PH * 2);
    unsigned short* attn    = (unsigned short*)alloc((size_t)PM * PH * 2);

    dim3 tb(32, 8);

    // 1. cast x -> bf16
    cast_f32_bf16_kernel<<<(PM * PH) / 4 / 256, 256, 0, stream>>>(x, xb, PM * PH);
    // 2. transpose weights -> bf16 B^T layouts  (out[c][r] = in[r][c])
    transpose_cast_kernel<<<dim3(PH / 32,  PH / 32),  tb, 0, stream>>>(wq,     wqT,    PH,  PH);
    transpose_cast_kernel<<<dim3(PLD / 32, PH / 32),  tb, 0, stream>>>(wk_lat, wkLatT, PH,  PLD);
    transpose_cast_kernel<<<dim3(PLD / 32, PH / 32),  tb, 0, stream>>>(wv_lat, wvLatT, PH,  PLD);
    transpose_cast_kernel<<<dim3(PH / 32,  PLD / 32), tb, 0, stream>>>(wk,     wkT,    PLD, PH);
    transpose_cast_kernel<<<dim3(PH / 32,  PLD / 32), tb, 0, stream>>>(wv,     wvT,    PLD, PH);
    transpose_cast_kernel<<<dim3(PH / 32,  PH / 32),  tb, 0, stream>>>(wo,     woT,    PH,  PH);

    // 3. projections
    gemm_bt_kernel<true, true ><<<dim3(PH  / 64, PM / 64), 256, 0, stream>>>(xb,   wqT,    bq,      qb,   PM, PH,  PH);
    gemm_bt_kernel<true, false><<<dim3(PLD / 64, PM / 64), 256, 0, stream>>>(xb,   wkLatT, nullptr, klat, PM, PLD, PH);
    gemm_bt_kernel<true, false><<<dim3(PLD / 64, PM / 64), 256, 0, stream>>>(xb,   wvLatT, nullptr, vlat, PM, PLD, PH);
    gemm_bt_kernel<true, false><<<dim3(PH  / 64, PM / 64), 256, 0, stream>>>(klat, wkT,    nullptr, kb,   PM, PH,  PLD);
    gemm_bt_kernel<true, false><<<dim3(PH  / 64, PM / 64), 256, 0, stream>>>(vlat, wvT,    nullptr, vb,   PM, PH,  PLD);

    // 4. causal flash attention
    flash_attn_kernel<<<PB * PNH * (PS / 16), 256, 0, stream>>>(qb, kb, vb, attn);

    // 5. output projection (fp32 out + bias)
    gemm_bt_kernel<false, true><<<dim3(PH / 64, PM / 64), 256, 0, stream>>>(attn, woT, bo, out, PM, PH, PH);
}

// Round 2
// 723.623 us; speedup vs baseline: 2.6929x; 2.6929x over previous
//
#include <hip/hip_runtime.h>
#include <hip/hip_bf16.h>

// ---------------- constants (problem shape) ----------------
// B=2, S=2048, H=2048, NH=16, LD=512, HD=128
#define PB   2
#define PS   2048
#define PH   2048
#define PNH  16
#define PLD  512
#define PHD  128
#define PM   (PB * PS)          // 4096 rows in all GEMMs
#define ATT_SCALE 0.08838834764831845f  // 1/sqrt(128)

typedef __attribute__((ext_vector_type(8))) short bf16x8;
typedef __attribute__((ext_vector_type(4))) float f32x4;

__device__ __forceinline__ float bf2f(unsigned int h) {
    return __uint_as_float(h << 16);
}
__device__ __forceinline__ unsigned short f2bf(float f) {
    unsigned int u = __float_as_uint(f);
    u += 0x7FFFu + ((u >> 16) & 1u);   // RNE
    return (unsigned short)(u >> 16);
}

// ---------------- cast fp32 -> bf16 (elementwise, 4/thread) ----------------
__global__ __launch_bounds__(256) void cast_f32_bf16_kernel(
    const float* __restrict__ in, unsigned short* __restrict__ out, int n)
{
    int i = (blockIdx.x * 256 + threadIdx.x) * 4;
    if (i >= n) return;
    float4 f = *(const float4*)(in + i);
    unsigned int a = (unsigned int)f2bf(f.x) | ((unsigned int)f2bf(f.y) << 16);
    unsigned int b = (unsigned int)f2bf(f.z) | ((unsigned int)f2bf(f.w) << 16);
    *(uint2*)(out + i) = make_uint2(a, b);
}

// ---------------- transpose + cast: in fp32 [R][C] -> out bf16 [C][R] ----------------
__global__ __launch_bounds__(256) void transpose_cast_kernel(
    const float* __restrict__ in, unsigned short* __restrict__ out, int R, int C)
{
    __shared__ float tile[32][33];
    int tx = threadIdx.x, ty = threadIdx.y;
    int r0 = blockIdx.y * 32, c0 = blockIdx.x * 32;
#pragma unroll
    for (int i = 0; i < 32; i += 8)
        tile[ty + i][tx] = in[(size_t)(r0 + ty + i) * C + (c0 + tx)];
    __syncthreads();
#pragma unroll
    for (int i = 0; i < 32; i += 8)
        out[(size_t)(c0 + ty + i) * R + (r0 + tx)] = f2bf(tile[tx][ty + i]);
}

// ---------------- bf16 transpose V: [B][S][NH*HD] -> [B][NH][HD][S] ----------------
__global__ __launch_bounds__(256) void transpose_v_kernel(
    const unsigned short* __restrict__ in, unsigned short* __restrict__ out)
{
    __shared__ unsigned short tile[32][34];
    int s0 = blockIdx.x * 32, d0 = blockIdx.y * 32;
    int bh = blockIdx.z;
    int b = bh >> 4, h = bh & 15;
    int tx = threadIdx.x, ty = threadIdx.y;   // 32 x 8
#pragma unroll
    for (int i = 0; i < 32; i += 8)
        tile[ty + i][tx] = in[(size_t)(b * PS + s0 + ty + i) * PH + h * PHD + d0 + tx];
    __syncthreads();
#pragma unroll
    for (int i = 0; i < 32; i += 8)
        out[(size_t)((b * PNH + h) * PHD + d0 + ty + i) * PS + s0 + tx] = tile[tx][ty + i];
}

// ---------------- bf16 MFMA GEMM: C[M][N] = A[M][K] @ B[K][N] (+bias) ----------------
template<bool BF16_OUT, bool HAS_BIAS>
__global__ __launch_bounds__(256) void gemm_bt_kernel(
    const unsigned short* __restrict__ A,
    const unsigned short* __restrict__ BT,
    const float* __restrict__ bias,
    void* __restrict__ Cout,
    int M, int N, int K)
{
    __shared__ __align__(16) unsigned short As[64 * 32];
    __shared__ __align__(16) unsigned short Bs[64 * 32];

    const int tid  = threadIdx.x;
    const int wave = tid >> 6;
    const int lane = tid & 63;
    const int wm = wave >> 1, wn = wave & 1;
    const int quad = lane >> 4, l15 = lane & 15;
    const int bm = blockIdx.y * 64, bn = blockIdx.x * 64;

    f32x4 acc[2][2] = {};

    const int lr = tid >> 2;          // 0..63 staging row
    const int lc = (tid & 3) * 8;     // 0,8,16,24 staging col
    const unsigned short* aptr = A  + (size_t)(bm + lr) * K + lc;
    const unsigned short* bptr = BT + (size_t)(bn + lr) * K + lc;

    for (int k0 = 0; k0 < K; k0 += 32) {
        *(bf16x8*)&As[lr * 32 + lc] = *(const bf16x8*)(aptr + k0);
        *(bf16x8*)&Bs[lr * 32 + lc] = *(const bf16x8*)(bptr + k0);
        __syncthreads();
        bf16x8 a0 = *(const bf16x8*)&As[(wm * 32 +      l15) * 32 + quad * 8];
        bf16x8 a1 = *(const bf16x8*)&As[(wm * 32 + 16 + l15) * 32 + quad * 8];
        bf16x8 b0 = *(const bf16x8*)&Bs[(wn * 32 +      l15) * 32 + quad * 8];
        bf16x8 b1 = *(const bf16x8*)&Bs[(wn * 32 + 16 + l15) * 32 + quad * 8];
        acc[0][0] = __builtin_amdgcn_mfma_f32_16x16x32_bf16(a0, b0, acc[0][0], 0, 0, 0);
        acc[0][1] = __builtin_amdgcn_mfma_f32_16x16x32_bf16(a0, b1, acc[0][1], 0, 0, 0);
        acc[1][0] = __builtin_amdgcn_mfma_f32_16x16x32_bf16(a1, b0, acc[1][0], 0, 0, 0);
        acc[1][1] = __builtin_amdgcn_mfma_f32_16x16x32_bf16(a1, b1, acc[1][1], 0, 0, 0);
        __syncthreads();
    }

#pragma unroll
    for (int mi = 0; mi < 2; ++mi)
#pragma unroll
        for (int ni = 0; ni < 2; ++ni)
#pragma unroll
            for (int r = 0; r < 4; ++r) {
                int row = bm + wm * 32 + mi * 16 + quad * 4 + r;  // C/D: row=quad*4+reg
                int col = bn + wn * 32 + ni * 16 + l15;           //      col=lane&15
                float val = acc[mi][ni][r];
                if (HAS_BIAS) val += bias[col];
                if (BF16_OUT)
                    ((unsigned short*)Cout)[(size_t)row * N + col] = f2bf(val);
                else
                    ((float*)Cout)[(size_t)row * N + col] = val;
            }
}

// ---------------- MFMA flash attention ----------------
// grid: B*NH*(S/64) blocks, 256 threads (4 waves x 16 queries).
// Q [B][S][H] bf16, K [B][S][H] bf16, Vt [B][NH][HD][S] bf16, O [B][S][H] bf16.
// Per iter: 64-key tile. QK^T and PV via mfma_f32_16x16x32_bf16.
// Online softmax fully in registers (rows live in quad lanes, shfl_xor<16 reduce).
__global__ __launch_bounds__(256) void flash_attn_mfma_kernel(
    const unsigned short* __restrict__ q,
    const unsigned short* __restrict__ k,
    const unsigned short* __restrict__ vt,
    unsigned short* __restrict__ o)
{
    // LDS: Qs (preamble) unioned with Ps (main loop): rows are wave-private.
    __shared__ __align__(16) unsigned short QPs[64][136];   // stride 272B: 2-way on frag reads
    __shared__ __align__(16) unsigned short Ks[64][136];
    __shared__ __align__(16) unsigned short Vts[128][72];   // [dim][key], stride 144B: 2-way

    const int tid  = threadIdx.x;
    const int wave = tid >> 6;
    const int lane = tid & 63;
    const int quad = lane >> 4, l15 = lane & 15;

    const int bid = blockIdx.x;
    const int qt = bid & 31;           // S/64 = 32
    const int h  = (bid >> 5) & 15;
    const int b  = bid >> 9;
    const int q0 = qt * 64;

    // ---- stage Q tile (each wave stages its own 16 rows) ----
    {
        int row = tid >> 2, c0 = (tid & 3) * 32;
        const unsigned short* src = q + (size_t)(b * PS + q0 + row) * PH + h * PHD + c0;
#pragma unroll
        for (int j = 0; j < 4; ++j)
            *(uint4*)&QPs[row][c0 + j * 8] = *(const uint4*)(src + j * 8);
    }
    __syncthreads();
    // preload Q A-frags into registers (4 k-chunks of 32)
    bf16x8 aq[4];
#pragma unroll
    for (int kk = 0; kk < 4; ++kk)
        aq[kk] = *(const bf16x8*)&QPs[wave * 16 + l15][kk * 32 + quad * 8];

    f32x4 oacc[8] = {};
    float m_prev[4], l_run[4];
#pragma unroll
    for (int r = 0; r < 4; ++r) { m_prev[r] = -1e30f; l_run[r] = 0.0f; }

    const int niter = qt + 1;
    for (int it = 0; it < niter; ++it) {
        const int k0 = it * 64;
        __syncthreads();  // prior-iter readers done before re-staging Ks/Vts
        // ---- stage K tile [64 keys][128 dims] ----
        {
            int row = tid >> 2, c0 = (tid & 3) * 32;
            const unsigned short* src = k + (size_t)(b * PS + k0 + row) * PH + h * PHD + c0;
#pragma unroll
            for (int j = 0; j < 4; ++j)
                *(uint4*)&Ks[row][c0 + j * 8] = *(const uint4*)(src + j * 8);
        }
        // ---- stage Vt tile [128 dims][64 keys] ----
        {
            int row = tid >> 1, c0 = (tid & 1) * 32;
            const unsigned short* src = vt + ((size_t)((b * PNH + h) * PHD + row)) * PS + k0 + c0;
#pragma unroll
            for (int j = 0; j < 4; ++j)
                *(uint4*)&Vts[row][c0 + j * 8] = *(const uint4*)(src + j * 8);
        }
        __syncthreads();

        // ---- S = Q K^T : 16 queries x 64 keys per wave ----
        f32x4 sacc[4] = {};
#pragma unroll
        for (int kk = 0; kk < 4; ++kk) {
#pragma unroll
            for (int n = 0; n < 4; ++n) {
                bf16x8 bk = *(const bf16x8*)&Ks[n * 16 + l15][kk * 32 + quad * 8];
                sacc[n] = __builtin_amdgcn_mfma_f32_16x16x32_bf16(aq[kk], bk, sacc[n], 0, 0, 0);
            }
        }

        // ---- scale + causal mask (only diagonal block needs it) ----
        float sraw[4][4];
        const bool diag = (k0 == q0);
#pragma unroll
        for (int n = 0; n < 4; ++n)
#pragma unroll
            for (int r = 0; r < 4; ++r) {
                float s = sacc[n][r] * ATT_SCALE;
                if (diag) {
                    int kg = n * 16 + l15;            // key rel to k0 (== q0)
                    int qg = wave * 16 + quad * 4 + r; // query rel to q0
                    if (kg > qg) s = -1e30f;
                }
                sraw[n][r] = s;
            }

        // ---- online softmax, register-resident ----
        float mx[4];
#pragma unroll
        for (int r = 0; r < 4; ++r)
            mx[r] = fmaxf(fmaxf(sraw[0][r], sraw[1][r]), fmaxf(sraw[2][r], sraw[3][r]));
#pragma unroll
        for (int sh = 1; sh < 16; sh <<= 1)
#pragma unroll
            for (int r = 0; r < 4; ++r)
                mx[r] = fmaxf(mx[r], __shfl_xor(mx[r], sh, 64));

        float alpha[4];
#pragma unroll
        for (int r = 0; r < 4; ++r) {
            float mn = fmaxf(m_prev[r], mx[r]);
            alpha[r] = __expf(m_prev[r] - mn);
            m_prev[r] = mn;
        }

        float rs[4] = {0, 0, 0, 0};
#pragma unroll
        for (int n = 0; n < 4; ++n)
#pragma unroll
            for (int r = 0; r < 4; ++r) {
                float p = __expf(sraw[n][r] - m_prev[r]);
                rs[r] += p;
                QPs[wave * 16 + quad * 4 + r][n * 16 + l15] = f2bf(p);  // wave-private rows
            }
#pragma unroll
        for (int sh = 1; sh < 16; sh <<= 1)
#pragma unroll
            for (int r = 0; r < 4; ++r)
                rs[r] += __shfl_xor(rs[r], sh, 64);
#pragma unroll
        for (int r = 0; r < 4; ++r)
            l_run[r] = l_run[r] * alpha[r] + rs[r];

        // ---- rescale O, then O += P V ----
#pragma unroll
        for (int n = 0; n < 8; ++n)
#pragma unroll
            for (int r = 0; r < 4; ++r)
                oacc[n][r] *= alpha[r];

#pragma unroll
        for (int kk = 0; kk < 2; ++kk) {
            bf16x8 ap = *(const bf16x8*)&QPs[wave * 16 + l15][kk * 32 + quad * 8];
#pragma unroll
            for (int n = 0; n < 8; ++n) {
                bf16x8 bv = *(const bf16x8*)&Vts[n * 16 + l15][kk * 32 + quad * 8];
                oacc[n] = __builtin_amdgcn_mfma_f32_16x16x32_bf16(ap, bv, oacc[n], 0, 0, 0);
            }
        }
    }

    // ---- epilogue: normalize, store bf16 ----
    float inv[4];
#pragma unroll
    for (int r = 0; r < 4; ++r) inv[r] = 1.0f / l_run[r];
#pragma unroll
    for (int n = 0; n < 8; ++n)
#pragma unroll
        for (int r = 0; r < 4; ++r) {
            int row = q0 + wave * 16 + quad * 4 + r;
            int col = h * PHD + n * 16 + l15;
            o[(size_t)(b * PS + row) * PH + col] = f2bf(oacc[n][r] * inv[r]);
        }
}

// ---------------- host launcher ----------------
extern "C" void kernel_launch(void* const* d_in, const int* in_sizes, int n_in,
                              void* d_out, int out_size, void* d_ws, size_t ws_size,
                              hipStream_t stream)
{
    const float* x      = (const float*)d_in[0];
    const float* wq     = (const float*)d_in[1];
    const float* bq     = (const float*)d_in[2];
    const float* wk_lat = (const float*)d_in[3];
    const float* wv_lat = (const float*)d_in[4];
    const float* wk     = (const float*)d_in[5];
    const float* wv     = (const float*)d_in[6];
    const float* wo     = (const float*)d_in[7];
    const float* bo     = (const float*)d_in[8];
    float* out = (float*)d_out;

    char* ws = (char*)d_ws;
    size_t off = 0;
    auto alloc = [&](size_t bytes) -> void* {
        void* p = ws + off;
        off += (bytes + 255) & ~(size_t)255;
        return p;
    };
    unsigned short* xb      = (unsigned short*)alloc((size_t)PM * PH * 2);
    unsigned short* wqT     = (unsigned short*)alloc((size_t)PH * PH * 2);
    unsigned short* wkLatT  = (unsigned short*)alloc((size_t)PLD * PH * 2);
    unsigned short* wvLatT  = (unsigned short*)alloc((size_t)PLD * PH * 2);
    unsigned short* wkT     = (unsigned short*)alloc((size_t)PH * PLD * 2);
    unsigned short* wvT     = (unsigned short*)alloc((size_t)PH * PLD * 2);
    unsigned short* woT     = (unsigned short*)alloc((size_t)PH * PH * 2);
    unsigned short* qb      = (unsigned short*)alloc((size_t)PM * PH * 2);
    unsigned short* klat    = (unsigned short*)alloc((size_t)PM * PLD * 2);
    unsigned short* vlat    = (unsigned short*)alloc((size_t)PM * PLD * 2);
    unsigned short* kb      = (unsigned short*)alloc((size_t)PM * PH * 2);
    unsigned short* vb      = (unsigned short*)alloc((size_t)PM * PH * 2);
    unsigned short* attn    = (unsigned short*)alloc((size_t)PM * PH * 2);
    // vt aliases xb: xb is dead after the first three GEMMs, vt is built after them.
    unsigned short* vt      = xb;

    dim3 tb(32, 8);

    // 1. cast x -> bf16
    cast_f32_bf16_kernel<<<(PM * PH) / 4 / 256, 256, 0, stream>>>(x, xb, PM * PH);
    // 2. transpose weights -> bf16 B^T layouts
    transpose_cast_kernel<<<dim3(PH / 32,  PH / 32),  tb, 0, stream>>>(wq,     wqT,    PH,  PH);
    transpose_cast_kernel<<<dim3(PLD / 32, PH / 32),  tb, 0, stream>>>(wk_lat, wkLatT, PH,  PLD);
    transpose_cast_kernel<<<dim3(PLD / 32, PH / 32),  tb, 0, stream>>>(wv_lat, wvLatT, PH,  PLD);
    transpose_cast_kernel<<<dim3(PH / 32,  PLD / 32), tb, 0, stream>>>(wk,     wkT,    PLD, PH);
    transpose_cast_kernel<<<dim3(PH / 32,  PLD / 32), tb, 0, stream>>>(wv,     wvT,    PLD, PH);
    transpose_cast_kernel<<<dim3(PH / 32,  PH / 32),  tb, 0, stream>>>(wo,     woT,    PH,  PH);

    // 3. projections
    gemm_bt_kernel<true, true ><<<dim3(PH  / 64, PM / 64), 256, 0, stream>>>(xb,   wqT,    bq,      qb,   PM, PH,  PH);
    gemm_bt_kernel<true, false><<<dim3(PLD / 64, PM / 64), 256, 0, stream>>>(xb,   wkLatT, nullptr, klat, PM, PLD, PH);
    gemm_bt_kernel<true, false><<<dim3(PLD / 64, PM / 64), 256, 0, stream>>>(xb,   wvLatT, nullptr, vlat, PM, PLD, PH);
    gemm_bt_kernel<true, false><<<dim3(PH  / 64, PM / 64), 256, 0, stream>>>(klat, wkT,    nullptr, kb,   PM, PH,  PLD);
    gemm_bt_kernel<true, false><<<dim3(PH  / 64, PM / 64), 256, 0, stream>>>(vlat, wvT,    nullptr, vb,   PM, PH,  PLD);

    // 3b. V -> V^T per head (for PV B-fragments)
    transpose_v_kernel<<<dim3(PS / 32, PHD / 32, PB * PNH), tb, 0, stream>>>(vb, vt);

    // 4. causal MFMA flash attention
    flash_attn_mfma_kernel<<<PB * PNH * (PS / 64), 256, 0, stream>>>(qb, kb, vt, attn);

    // 5. output projection (fp32 out + bias)
    gemm_bt_kernel<false, true><<<dim3(PH / 64, PM / 64), 256, 0, stream>>>(attn, woT, bo, out, PM, PH, PH);
}

// Round 3
// 644.224 us; speedup vs baseline: 3.0248x; 1.1232x over previous
//
#include <hip/hip_runtime.h>
#include <hip/hip_bf16.h>

// ---------------- constants (problem shape) ----------------
// B=2, S=2048, H=2048, NH=16, LD=512, HD=128
#define PB   2
#define PS   2048
#define PH   2048
#define PNH  16
#define PLD  512
#define PHD  128
#define PM   (PB * PS)          // 4096 rows in all GEMMs
#define ATT_SCALE 0.08838834764831845f  // 1/sqrt(128)

typedef __attribute__((ext_vector_type(8))) short bf16x8;
typedef __attribute__((ext_vector_type(4))) float f32x4;

__device__ __forceinline__ float bf2f(unsigned int h) {
    return __uint_as_float(h << 16);
}
__device__ __forceinline__ unsigned short f2bf(float f) {
    unsigned int u = __float_as_uint(f);
    u += 0x7FFFu + ((u >> 16) & 1u);   // RNE
    return (unsigned short)(u >> 16);
}

// async global->LDS, 16 B per lane; LDS dest = wave-uniform base + lane*16
__device__ __forceinline__ void gl_lds16(const unsigned short* g, unsigned short* l) {
    __builtin_amdgcn_global_load_lds(
        (const __attribute__((address_space(1))) unsigned int*)g,
        (__attribute__((address_space(3))) unsigned int*)l, 16, 0, 0);
}

// ---------------- cast fp32 -> bf16 (elementwise, 4/thread) ----------------
__global__ __launch_bounds__(256) void cast_f32_bf16_kernel(
    const float* __restrict__ in, unsigned short* __restrict__ out, int n)
{
    int i = (blockIdx.x * 256 + threadIdx.x) * 4;
    if (i >= n) return;
    float4 f = *(const float4*)(in + i);
    unsigned int a = (unsigned int)f2bf(f.x) | ((unsigned int)f2bf(f.y) << 16);
    unsigned int b = (unsigned int)f2bf(f.z) | ((unsigned int)f2bf(f.w) << 16);
    *(uint2*)(out + i) = make_uint2(a, b);
}

// ---------------- transpose + cast: in fp32 [R][C] -> out bf16 [C][R] ----------------
__global__ __launch_bounds__(256) void transpose_cast_kernel(
    const float* __restrict__ in, unsigned short* __restrict__ out, int R, int C)
{
    __shared__ float tile[32][33];
    int tx = threadIdx.x, ty = threadIdx.y;
    int r0 = blockIdx.y * 32, c0 = blockIdx.x * 32;
#pragma unroll
    for (int i = 0; i < 32; i += 8)
        tile[ty + i][tx] = in[(size_t)(r0 + ty + i) * C + (c0 + tx)];
    __syncthreads();
#pragma unroll
    for (int i = 0; i < 32; i += 8)
        out[(size_t)(c0 + ty + i) * R + (r0 + tx)] = f2bf(tile[tx][ty + i]);
}

// ---------------- bf16 transpose V: [B][S][NH*HD] -> [B][NH][HD][S] ----------------
__global__ __launch_bounds__(256) void transpose_v_kernel(
    const unsigned short* __restrict__ in, unsigned short* __restrict__ out)
{
    __shared__ unsigned short tile[32][34];
    int s0 = blockIdx.x * 32, d0 = blockIdx.y * 32;
    int bh = blockIdx.z;
    int b = bh >> 4, h = bh & 15;
    int tx = threadIdx.x, ty = threadIdx.y;   // 32 x 8
#pragma unroll
    for (int i = 0; i < 32; i += 8)
        tile[ty + i][tx] = in[(size_t)(b * PS + s0 + ty + i) * PH + h * PHD + d0 + tx];
    __syncthreads();
#pragma unroll
    for (int i = 0; i < 32; i += 8)
        out[(size_t)((b * PNH + h) * PHD + d0 + ty + i) * PS + s0 + tx] = tile[tx][ty + i];
}

// ---------------- 64-tile bf16 MFMA GEMM (kept for N=512 GEMMs) ----------------
template<bool BF16_OUT, bool HAS_BIAS>
__global__ __launch_bounds__(256) void gemm_bt_kernel(
    const unsigned short* __restrict__ A,
    const unsigned short* __restrict__ BT,
    const float* __restrict__ bias,
    void* __restrict__ Cout,
    int M, int N, int K)
{
    __shared__ __align__(16) unsigned short As[64 * 32];
    __shared__ __align__(16) unsigned short Bs[64 * 32];

    const int tid  = threadIdx.x;
    const int wave = tid >> 6;
    const int lane = tid & 63;
    const int wm = wave >> 1, wn = wave & 1;
    const int quad = lane >> 4, l15 = lane & 15;
    const int bm = blockIdx.y * 64, bn = blockIdx.x * 64;

    f32x4 acc[2][2] = {};

    // staging: wave w stages rows w*16..w*16+15 of A and B; lane l -> row w*16+(l>>2), col (l&3)*8
    const int lr = tid >> 2;
    const int lc = (tid & 3) * 8;
    const unsigned short* aptr = A  + (size_t)(bm + lr) * K + lc;
    const unsigned short* bptr = BT + (size_t)(bn + lr) * K + lc;
    unsigned short* aL = &As[wave * 16 * 32];
    unsigned short* bL = &Bs[wave * 16 * 32];

    for (int k0 = 0; k0 < K; k0 += 32) {
        gl_lds16(aptr + k0, aL);
        gl_lds16(bptr + k0, bL);
        __syncthreads();
        bf16x8 a0 = *(const bf16x8*)&As[(wm * 32 +      l15) * 32 + quad * 8];
        bf16x8 a1 = *(const bf16x8*)&As[(wm * 32 + 16 + l15) * 32 + quad * 8];
        bf16x8 b0 = *(const bf16x8*)&Bs[(wn * 32 +      l15) * 32 + quad * 8];
        bf16x8 b1 = *(const bf16x8*)&Bs[(wn * 32 + 16 + l15) * 32 + quad * 8];
        acc[0][0] = __builtin_amdgcn_mfma_f32_16x16x32_bf16(a0, b0, acc[0][0], 0, 0, 0);
        acc[0][1] = __builtin_amdgcn_mfma_f32_16x16x32_bf16(a0, b1, acc[0][1], 0, 0, 0);
        acc[1][0] = __builtin_amdgcn_mfma_f32_16x16x32_bf16(a1, b0, acc[1][0], 0, 0, 0);
        acc[1][1] = __builtin_amdgcn_mfma_f32_16x16x32_bf16(a1, b1, acc[1][1], 0, 0, 0);
        __syncthreads();
    }

#pragma unroll
    for (int mi = 0; mi < 2; ++mi)
#pragma unroll
        for (int ni = 0; ni < 2; ++ni)
#pragma unroll
            for (int r = 0; r < 4; ++r) {
                int row = bm + wm * 32 + mi * 16 + quad * 4 + r;
                int col = bn + wn * 32 + ni * 16 + l15;
                float val = acc[mi][ni][r];
                if (HAS_BIAS) val += bias[col];
                if (BF16_OUT)
                    ((unsigned short*)Cout)[(size_t)row * N + col] = f2bf(val);
                else
                    ((float*)Cout)[(size_t)row * N + col] = val;
            }
}

// ---------------- 128-tile bf16 MFMA GEMM (m97 structure) ----------------
// grid (N/128, M/128), 256 threads. 2x2 waves, each wave 64x64 = 4x4 MFMA frags.
template<bool BF16_OUT, bool HAS_BIAS>
__global__ __launch_bounds__(256) void gemm_bt128_kernel(
    const unsigned short* __restrict__ A,
    const unsigned short* __restrict__ BT,
    const float* __restrict__ bias,
    void* __restrict__ Cout,
    int M, int N, int K)
{
    __shared__ __align__(16) unsigned short As[128 * 32];
    __shared__ __align__(16) unsigned short Bs[128 * 32];

    const int tid  = threadIdx.x;
    const int wave = tid >> 6;
    const int lane = tid & 63;
    const int wm = wave >> 1, wn = wave & 1;
    const int quad = lane >> 4, l15 = lane & 15;
    const int bm = blockIdx.y * 128, bn = blockIdx.x * 128;

    f32x4 acc[4][4] = {};

    // staging: wave w stages rows w*32..w*32+31; two gl_lds16 per matrix
    const int srow = wave * 32 + (lane >> 2);
    const int scol = (lane & 3) * 8;
    const unsigned short* aG = A  + (size_t)(bm + srow) * K + scol;
    const unsigned short* bG = BT + (size_t)(bn + srow) * K + scol;
    unsigned short* aL = &As[wave * 32 * 32];
    unsigned short* bL = &Bs[wave * 32 * 32];

    for (int k0 = 0; k0 < K; k0 += 32) {
        gl_lds16(aG + k0,                    aL);
        gl_lds16(aG + k0 + (size_t)16 * K,   aL + 16 * 32);
        gl_lds16(bG + k0,                    bL);
        gl_lds16(bG + k0 + (size_t)16 * K,   bL + 16 * 32);
        __syncthreads();
        bf16x8 af[4], bfr[4];
#pragma unroll
        for (int i = 0; i < 4; ++i) {
            af[i]  = *(const bf16x8*)&As[(wm * 64 + i * 16 + l15) * 32 + quad * 8];
            bfr[i] = *(const bf16x8*)&Bs[(wn * 64 + i * 16 + l15) * 32 + quad * 8];
        }
#pragma unroll
        for (int i = 0; i < 4; ++i)
#pragma unroll
            for (int j = 0; j < 4; ++j)
                acc[i][j] = __builtin_amdgcn_mfma_f32_16x16x32_bf16(af[i], bfr[j], acc[i][j], 0, 0, 0);
        __syncthreads();
    }

#pragma unroll
    for (int i = 0; i < 4; ++i)
#pragma unroll
        for (int j = 0; j < 4; ++j)
#pragma unroll
            for (int r = 0; r < 4; ++r) {
                int row = bm + wm * 64 + i * 16 + quad * 4 + r;
                int col = bn + wn * 64 + j * 16 + l15;
                float val = acc[i][j][r];
                if (HAS_BIAS) val += bias[col];
                if (BF16_OUT)
                    ((unsigned short*)Cout)[(size_t)row * N + col] = f2bf(val);
                else
                    ((float*)Cout)[(size_t)row * N + col] = val;
            }
}

// ---------------- MFMA flash attention, barrier-free ----------------
// grid 1024 blocks, 256 threads (4 waves x 16 queries = 64-query tile).
// All MFMA fragments except P read directly from global (L1/L2-cached).
// Only LDS use: wave-private P transpose (C-layout -> A-layout). No __syncthreads.
__global__ __launch_bounds__(256, 4) void flash_attn_mfma_kernel(
    const unsigned short* __restrict__ q,
    const unsigned short* __restrict__ k,
    const unsigned short* __restrict__ vt,
    unsigned short* __restrict__ o)
{
    __shared__ __align__(16) unsigned short Ps[4][16][72];  // [wave][query][key], 144B stride

    const int tid  = threadIdx.x;
    const int wave = tid >> 6;
    const int lane = tid & 63;
    const int quad = lane >> 4, l15 = lane & 15;

    const int bid = blockIdx.x;
    const int qt = 31 - (bid >> 5);     // longest tiles dispatch first
    const int bh = bid & 31;            // consecutive bids -> different heads -> head pinned to one XCD-L2
    const int b  = bh >> 4, h = bh & 15;
    const int q0 = qt * 64;

    const unsigned short* qbase = q  + (size_t)(b * PS + q0) * PH + h * PHD;
    const unsigned short* kbase = k  + (size_t)b * PS * PH + h * PHD;
    const unsigned short* vbase = vt + (size_t)(b * PNH + h) * PHD * PS;

    // Q A-frags: 16 queries per wave, registers for whole kernel
    bf16x8 aq[4];
#pragma unroll
    for (int kk = 0; kk < 4; ++kk)
        aq[kk] = *(const bf16x8*)(qbase + (size_t)(wave * 16 + l15) * PH + kk * 32 + quad * 8);

    f32x4 oacc[8] = {};
    float m_prev[4], l_run[4];
#pragma unroll
    for (int r = 0; r < 4; ++r) { m_prev[r] = -1e30f; l_run[r] = 0.0f; }

    for (int it = 0; it <= qt; ++it) {
        const int k0 = it * 64;

        // ---- S = Q K^T : K B-frags straight from global ----
        f32x4 sacc[4] = {};
#pragma unroll
        for (int kk = 0; kk < 4; ++kk)
#pragma unroll
            for (int n = 0; n < 4; ++n) {
                bf16x8 bk = *(const bf16x8*)(kbase + (size_t)(k0 + n * 16 + l15) * PH + kk * 32 + quad * 8);
                sacc[n] = __builtin_amdgcn_mfma_f32_16x16x32_bf16(aq[kk], bk, sacc[n], 0, 0, 0);
            }

        // ---- scale + causal mask (diagonal tile only) ----
        float sraw[4][4];
        const bool diag = (k0 == q0);
#pragma unroll
        for (int n = 0; n < 4; ++n)
#pragma unroll
            for (int r = 0; r < 4; ++r) {
                float s = sacc[n][r] * ATT_SCALE;
                if (diag) {
                    int kg = n * 16 + l15;
                    int qg = wave * 16 + quad * 4 + r;
                    if (kg > qg) s = -1e30f;
                }
                sraw[n][r] = s;
            }

        // ---- online softmax, register-resident ----
        float mx[4];
#pragma unroll
        for (int r = 0; r < 4; ++r)
            mx[r] = fmaxf(fmaxf(sraw[0][r], sraw[1][r]), fmaxf(sraw[2][r], sraw[3][r]));
#pragma unroll
        for (int sh = 1; sh < 16; sh <<= 1)
#pragma unroll
            for (int r = 0; r < 4; ++r)
                mx[r] = fmaxf(mx[r], __shfl_xor(mx[r], sh, 64));

        float alpha[4];
#pragma unroll
        for (int r = 0; r < 4; ++r) {
            float mn = fmaxf(m_prev[r], mx[r]);
            alpha[r] = __expf(m_prev[r] - mn);
            m_prev[r] = mn;
        }

        float rs[4] = {0, 0, 0, 0};
#pragma unroll
        for (int n = 0; n < 4; ++n)
#pragma unroll
            for (int r = 0; r < 4; ++r) {
                float p = __expf(sraw[n][r] - m_prev[r]);
                rs[r] += p;
                Ps[wave][quad * 4 + r][n * 16 + l15] = f2bf(p);  // wave-private: no barrier
            }
#pragma unroll
        for (int sh = 1; sh < 16; sh <<= 1)
#pragma unroll
            for (int r = 0; r < 4; ++r)
                rs[r] += __shfl_xor(rs[r], sh, 64);
#pragma unroll
        for (int r = 0; r < 4; ++r)
            l_run[r] = l_run[r] * alpha[r] + rs[r];

        // ---- rescale O, then O += P V (V B-frags straight from global) ----
#pragma unroll
        for (int n = 0; n < 8; ++n)
#pragma unroll
            for (int r = 0; r < 4; ++r)
                oacc[n][r] *= alpha[r];

#pragma unroll
        for (int kk = 0; kk < 2; ++kk) {
            bf16x8 ap = *(const bf16x8*)&Ps[wave][l15][kk * 32 + quad * 8];
#pragma unroll
            for (int n = 0; n < 8; ++n) {
                bf16x8 bv = *(const bf16x8*)(vbase + (size_t)(n * 16 + l15) * PS + k0 + kk * 32 + quad * 8);
                oacc[n] = __builtin_amdgcn_mfma_f32_16x16x32_bf16(ap, bv, oacc[n], 0, 0, 0);
            }
        }
    }

    // ---- epilogue: normalize, store bf16 ----
    float inv[4];
#pragma unroll
    for (int r = 0; r < 4; ++r) inv[r] = 1.0f / l_run[r];
#pragma unroll
    for (int n = 0; n < 8; ++n)
#pragma unroll
        for (int r = 0; r < 4; ++r) {
            int row = q0 + wave * 16 + quad * 4 + r;
            int col = h * PHD + n * 16 + l15;
            o[(size_t)(b * PS + row) * PH + col] = f2bf(oacc[n][r] * inv[r]);
        }
}

// ---------------- host launcher ----------------
extern "C" void kernel_launch(void* const* d_in, const int* in_sizes, int n_in,
                              void* d_out, int out_size, void* d_ws, size_t ws_size,
                              hipStream_t stream)
{
    const float* x      = (const float*)d_in[0];
    const float* wq     = (const float*)d_in[1];
    const float* bq     = (const float*)d_in[2];
    const float* wk_lat = (const float*)d_in[3];
    const float* wv_lat = (const float*)d_in[4];
    const float* wk     = (const float*)d_in[5];
    const float* wv     = (const float*)d_in[6];
    const float* wo     = (const float*)d_in[7];
    const float* bo     = (const float*)d_in[8];
    float* out = (float*)d_out;

    char* ws = (char*)d_ws;
    size_t off = 0;
    auto alloc = [&](size_t bytes) -> void* {
        void* p = ws + off;
        off += (bytes + 255) & ~(size_t)255;
        return p;
    };
    unsigned short* xb      = (unsigned short*)alloc((size_t)PM * PH * 2);
    unsigned short* wqT     = (unsigned short*)alloc((size_t)PH * PH * 2);
    unsigned short* wkLatT  = (unsigned short*)alloc((size_t)PLD * PH * 2);
    unsigned short* wvLatT  = (unsigned short*)alloc((size_t)PLD * PH * 2);
    unsigned short* wkT     = (unsigned short*)alloc((size_t)PH * PLD * 2);
    unsigned short* wvT     = (unsigned short*)alloc((size_t)PH * PLD * 2);
    unsigned short* woT     = (unsigned short*)alloc((size_t)PH * PH * 2);
    unsigned short* qb      = (unsigned short*)alloc((size_t)PM * PH * 2);
    unsigned short* klat    = (unsigned short*)alloc((size_t)PM * PLD * 2);
    unsigned short* vlat    = (unsigned short*)alloc((size_t)PM * PLD * 2);
    unsigned short* kb      = (unsigned short*)alloc((size_t)PM * PH * 2);
    unsigned short* vb      = (unsigned short*)alloc((size_t)PM * PH * 2);
    unsigned short* attn    = (unsigned short*)alloc((size_t)PM * PH * 2);
    // vt aliases xb: xb dead after the three GEMMs reading it; vt built after them.
    unsigned short* vt      = xb;

    dim3 tb(32, 8);

    // 1. cast x -> bf16
    cast_f32_bf16_kernel<<<(PM * PH) / 4 / 256, 256, 0, stream>>>(x, xb, PM * PH);
    // 2. transpose weights -> bf16 B^T layouts
    transpose_cast_kernel<<<dim3(PH / 32,  PH / 32),  tb, 0, stream>>>(wq,     wqT,    PH,  PH);
    transpose_cast_kernel<<<dim3(PLD / 32, PH / 32),  tb, 0, stream>>>(wk_lat, wkLatT, PH,  PLD);
    transpose_cast_kernel<<<dim3(PLD / 32, PH / 32),  tb, 0, stream>>>(wv_lat, wvLatT, PH,  PLD);
    transpose_cast_kernel<<<dim3(PH / 32,  PLD / 32), tb, 0, stream>>>(wk,     wkT,    PLD, PH);
    transpose_cast_kernel<<<dim3(PH / 32,  PLD / 32), tb, 0, stream>>>(wv,     wvT,    PLD, PH);
    transpose_cast_kernel<<<dim3(PH / 32,  PH / 32),  tb, 0, stream>>>(wo,     woT,    PH,  PH);

    // 3. projections (128-tile for N>=2048, 64-tile for N=512)
    gemm_bt128_kernel<true, true ><<<dim3(PH / 128,  PM / 128), 256, 0, stream>>>(xb,   wqT,    bq,      qb,   PM, PH,  PH);
    gemm_bt_kernel   <true, false><<<dim3(PLD / 64,  PM / 64),  256, 0, stream>>>(xb,   wkLatT, nullptr, klat, PM, PLD, PH);
    gemm_bt_kernel   <true, false><<<dim3(PLD / 64,  PM / 64),  256, 0, stream>>>(xb,   wvLatT, nullptr, vlat, PM, PLD, PH);
    gemm_bt128_kernel<true, false><<<dim3(PH / 128,  PM / 128), 256, 0, stream>>>(klat, wkT,    nullptr, kb,   PM, PH,  PLD);
    gemm_bt128_kernel<true, false><<<dim3(PH / 128,  PM / 128), 256, 0, stream>>>(vlat, wvT,    nullptr, vb,   PM, PH,  PLD);

    // 3b. V -> V^T per head (PV B-fragments read [dim][key] contiguous)
    transpose_v_kernel<<<dim3(PS / 32, PHD / 32, PB * PNH), tb, 0, stream>>>(vb, vt);

    // 4. causal MFMA flash attention (barrier-free)
    flash_attn_mfma_kernel<<<PB * PNH * (PS / 64), 256, 0, stream>>>(qb, kb, vt, attn);

    // 5. output projection (fp32 out + bias)
    gemm_bt128_kernel<false, true><<<dim3(PH / 128, PM / 128), 256, 0, stream>>>(attn, woT, bo, out, PM, PH, PH);
}

// Round 4
// 600.733 us; speedup vs baseline: 3.2438x; 1.0724x over previous
//
#include <hip/hip_runtime.h>
#include <hip/hip_bf16.h>

// ---------------- constants (problem shape) ----------------
// B=2, S=2048, H=2048, NH=16, LD=512, HD=128
#define PB   2
#define PS   2048
#define PH   2048
#define PNH  16
#define PLD  512
#define PHD  128
#define PM   (PB * PS)          // 4096 rows in all GEMMs
#define ATT_SCALE 0.08838834764831845f  // 1/sqrt(128)

typedef __attribute__((ext_vector_type(8))) short bf16x8;
typedef __attribute__((ext_vector_type(4))) float f32x4;

__device__ __forceinline__ float bf2f(unsigned int h) {
    return __uint_as_float(h << 16);
}
__device__ __forceinline__ unsigned short f2bf(float f) {
    unsigned int u = __float_as_uint(f);
    u += 0x7FFFu + ((u >> 16) & 1u);   // RNE
    return (unsigned short)(u >> 16);
}

// async global->LDS, 16 B per lane; LDS dest = wave-uniform base + lane*16
__device__ __forceinline__ void gl_lds16(const unsigned short* g, unsigned short* l) {
    __builtin_amdgcn_global_load_lds(
        (const __attribute__((address_space(1))) unsigned int*)g,
        (__attribute__((address_space(3))) unsigned int*)l, 16, 0, 0);
}

// ---------------- cast fp32 -> bf16 (elementwise, 4/thread) ----------------
__global__ __launch_bounds__(256) void cast_f32_bf16_kernel(
    const float* __restrict__ in, unsigned short* __restrict__ out, int n)
{
    int i = (blockIdx.x * 256 + threadIdx.x) * 4;
    if (i >= n) return;
    float4 f = *(const float4*)(in + i);
    unsigned int a = (unsigned int)f2bf(f.x) | ((unsigned int)f2bf(f.y) << 16);
    unsigned int b = (unsigned int)f2bf(f.z) | ((unsigned int)f2bf(f.w) << 16);
    *(uint2*)(out + i) = make_uint2(a, b);
}

// ---------------- transpose + cast: in fp32 [R][C] -> out bf16 [C][R] ----------------
__global__ __launch_bounds__(256) void transpose_cast_kernel(
    const float* __restrict__ in, unsigned short* __restrict__ out, int R, int C)
{
    __shared__ float tile[32][33];
    int tx = threadIdx.x, ty = threadIdx.y;
    int r0 = blockIdx.y * 32, c0 = blockIdx.x * 32;
#pragma unroll
    for (int i = 0; i < 32; i += 8)
        tile[ty + i][tx] = in[(size_t)(r0 + ty + i) * C + (c0 + tx)];
    __syncthreads();
#pragma unroll
    for (int i = 0; i < 32; i += 8)
        out[(size_t)(c0 + ty + i) * R + (r0 + tx)] = f2bf(tile[tx][ty + i]);
}

// ---------------- bf16 transpose V: [B][S][NH*HD] -> [B][NH][HD][S] ----------------
__global__ __launch_bounds__(256) void transpose_v_kernel(
    const unsigned short* __restrict__ in, unsigned short* __restrict__ out)
{
    __shared__ unsigned short tile[32][34];
    int s0 = blockIdx.x * 32, d0 = blockIdx.y * 32;
    int bh = blockIdx.z;
    int b = bh >> 4, h = bh & 15;
    int tx = threadIdx.x, ty = threadIdx.y;   // 32 x 8
#pragma unroll
    for (int i = 0; i < 32; i += 8)
        tile[ty + i][tx] = in[(size_t)(b * PS + s0 + ty + i) * PH + h * PHD + d0 + tx];
    __syncthreads();
#pragma unroll
    for (int i = 0; i < 32; i += 8)
        out[(size_t)((b * PNH + h) * PHD + d0 + ty + i) * PS + s0 + tx] = tile[tx][ty + i];
}

// ---------------- 64-tile bf16 MFMA GEMM (kept for N=512 GEMMs) ----------------
template<bool BF16_OUT, bool HAS_BIAS>
__global__ __launch_bounds__(256) void gemm_bt_kernel(
    const unsigned short* __restrict__ A,
    const unsigned short* __restrict__ BT,
    const float* __restrict__ bias,
    void* __restrict__ Cout,
    int M, int N, int K)
{
    __shared__ __align__(16) unsigned short As[64 * 32];
    __shared__ __align__(16) unsigned short Bs[64 * 32];

    const int tid  = threadIdx.x;
    const int wave = tid >> 6;
    const int lane = tid & 63;
    const int wm = wave >> 1, wn = wave & 1;
    const int quad = lane >> 4, l15 = lane & 15;
    const int bm = blockIdx.y * 64, bn = blockIdx.x * 64;

    f32x4 acc[2][2] = {};

    const int lr = tid >> 2;
    const int lc = (tid & 3) * 8;
    const unsigned short* aptr = A  + (size_t)(bm + lr) * K + lc;
    const unsigned short* bptr = BT + (size_t)(bn + lr) * K + lc;
    unsigned short* aL = &As[wave * 16 * 32];
    unsigned short* bL = &Bs[wave * 16 * 32];

    for (int k0 = 0; k0 < K; k0 += 32) {
        gl_lds16(aptr + k0, aL);
        gl_lds16(bptr + k0, bL);
        __syncthreads();
        bf16x8 a0 = *(const bf16x8*)&As[(wm * 32 +      l15) * 32 + quad * 8];
        bf16x8 a1 = *(const bf16x8*)&As[(wm * 32 + 16 + l15) * 32 + quad * 8];
        bf16x8 b0 = *(const bf16x8*)&Bs[(wn * 32 +      l15) * 32 + quad * 8];
        bf16x8 b1 = *(const bf16x8*)&Bs[(wn * 32 + 16 + l15) * 32 + quad * 8];
        acc[0][0] = __builtin_amdgcn_mfma_f32_16x16x32_bf16(a0, b0, acc[0][0], 0, 0, 0);
        acc[0][1] = __builtin_amdgcn_mfma_f32_16x16x32_bf16(a0, b1, acc[0][1], 0, 0, 0);
        acc[1][0] = __builtin_amdgcn_mfma_f32_16x16x32_bf16(a1, b0, acc[1][0], 0, 0, 0);
        acc[1][1] = __builtin_amdgcn_mfma_f32_16x16x32_bf16(a1, b1, acc[1][1], 0, 0, 0);
        __syncthreads();
    }

#pragma unroll
    for (int mi = 0; mi < 2; ++mi)
#pragma unroll
        for (int ni = 0; ni < 2; ++ni)
#pragma unroll
            for (int r = 0; r < 4; ++r) {
                int row = bm + wm * 32 + mi * 16 + quad * 4 + r;
                int col = bn + wn * 32 + ni * 16 + l15;
                float val = acc[mi][ni][r];
                if (HAS_BIAS) val += bias[col];
                if (BF16_OUT)
                    ((unsigned short*)Cout)[(size_t)row * N + col] = f2bf(val);
                else
                    ((float*)Cout)[(size_t)row * N + col] = val;
            }
}

// ---------------- 128-tile bf16 MFMA GEMM (m97 structure) ----------------
template<bool BF16_OUT, bool HAS_BIAS>
__global__ __launch_bounds__(256) void gemm_bt128_kernel(
    const unsigned short* __restrict__ A,
    const unsigned short* __restrict__ BT,
    const float* __restrict__ bias,
    void* __restrict__ Cout,
    int M, int N, int K)
{
    __shared__ __align__(16) unsigned short As[128 * 32];
    __shared__ __align__(16) unsigned short Bs[128 * 32];

    const int tid  = threadIdx.x;
    const int wave = tid >> 6;
    const int lane = tid & 63;
    const int wm = wave >> 1, wn = wave & 1;
    const int quad = lane >> 4, l15 = lane & 15;
    const int bm = blockIdx.y * 128, bn = blockIdx.x * 128;

    f32x4 acc[4][4] = {};

    const int srow = wave * 32 + (lane >> 2);
    const int scol = (lane & 3) * 8;
    const unsigned short* aG = A  + (size_t)(bm + srow) * K + scol;
    const unsigned short* bG = BT + (size_t)(bn + srow) * K + scol;
    unsigned short* aL = &As[wave * 32 * 32];
    unsigned short* bL = &Bs[wave * 32 * 32];

    for (int k0 = 0; k0 < K; k0 += 32) {
        gl_lds16(aG + k0,                    aL);
        gl_lds16(aG + k0 + (size_t)16 * K,   aL + 16 * 32);
        gl_lds16(bG + k0,                    bL);
        gl_lds16(bG + k0 + (size_t)16 * K,   bL + 16 * 32);
        __syncthreads();
        bf16x8 af[4], bfr[4];
#pragma unroll
        for (int i = 0; i < 4; ++i) {
            af[i]  = *(const bf16x8*)&As[(wm * 64 + i * 16 + l15) * 32 + quad * 8];
            bfr[i] = *(const bf16x8*)&Bs[(wn * 64 + i * 16 + l15) * 32 + quad * 8];
        }
#pragma unroll
        for (int i = 0; i < 4; ++i)
#pragma unroll
            for (int j = 0; j < 4; ++j)
                acc[i][j] = __builtin_amdgcn_mfma_f32_16x16x32_bf16(af[i], bfr[j], acc[i][j], 0, 0, 0);
        __syncthreads();
    }

#pragma unroll
    for (int i = 0; i < 4; ++i)
#pragma unroll
        for (int j = 0; j < 4; ++j)
#pragma unroll
            for (int r = 0; r < 4; ++r) {
                int row = bm + wm * 64 + i * 16 + quad * 4 + r;
                int col = bn + wn * 64 + j * 16 + l15;
                float val = acc[i][j][r];
                if (HAS_BIAS) val += bias[col];
                if (BF16_OUT)
                    ((unsigned short*)Cout)[(size_t)row * N + col] = f2bf(val);
                else
                    ((float*)Cout)[(size_t)row * N + col] = val;
            }
}

// ---------------- MFMA flash attention, barrier-free, register-pipelined ----------------
// grid 1024 blocks, 256 threads (4 waves x 16 queries = 64-query tile).
// kf[16]: next-iter K fragments (prefetched one iteration ahead).
// vf[16]: this-iter V fragments (issued at loop top, consumed after softmax).
// Only LDS: wave-private P transpose. No __syncthreads. VGPR cap 256 (2 waves/EU).
__global__ __launch_bounds__(256, 2) void flash_attn_mfma_kernel(
    const unsigned short* __restrict__ q,
    const unsigned short* __restrict__ k,
    const unsigned short* __restrict__ vt,
    unsigned short* __restrict__ o)
{
    __shared__ __align__(16) unsigned short Ps[4][16][72];  // [wave][query][key], 144B stride

    const int tid  = threadIdx.x;
    const int wave = tid >> 6;
    const int lane = tid & 63;
    const int quad = lane >> 4, l15 = lane & 15;

    const int bid = blockIdx.x;
    const int qt = 31 - (bid >> 5);     // longest tiles dispatch first
    const int bh = bid & 31;            // same head -> bid%8 const -> same XCD L2
    const int b  = bh >> 4, h = bh & 15;
    const int q0 = qt * 64;

    const unsigned short* qbase = q  + (size_t)(b * PS + q0) * PH + h * PHD;
    const unsigned short* kbase = k  + (size_t)b * PS * PH + h * PHD;
    const unsigned short* vbase = vt + (size_t)(b * PNH + h) * PHD * PS;

    // Q A-frags: registers for whole kernel
    bf16x8 aq[4];
#pragma unroll
    for (int kk = 0; kk < 4; ++kk)
        aq[kk] = *(const bf16x8*)(qbase + (size_t)(wave * 16 + l15) * PH + kk * 32 + quad * 8);

    f32x4 oacc[8] = {};
    float m_prev[4], l_run[4];
#pragma unroll
    for (int r = 0; r < 4; ++r) { m_prev[r] = -1e30f; l_run[r] = 0.0f; }

    // preload K fragments for iteration 0
    bf16x8 kf[16];
#pragma unroll
    for (int kk = 0; kk < 4; ++kk)
#pragma unroll
        for (int n = 0; n < 4; ++n)
            kf[kk * 4 + n] = *(const bf16x8*)(kbase + (size_t)(n * 16 + l15) * PH + kk * 32 + quad * 8);

    for (int it = 0; it <= qt; ++it) {
        const int k0 = it * 64;

        // ---- issue this-iter V fragment loads (consumed after softmax) ----
        bf16x8 vf[16];
#pragma unroll
        for (int kk = 0; kk < 2; ++kk)
#pragma unroll
            for (int n = 0; n < 8; ++n)
                vf[kk * 8 + n] = *(const bf16x8*)(vbase + (size_t)(n * 16 + l15) * PS + k0 + kk * 32 + quad * 8);

        // ---- S = Q K^T from register fragments ----
        f32x4 sacc[4] = {};
#pragma unroll
        for (int kk = 0; kk < 4; ++kk)
#pragma unroll
            for (int n = 0; n < 4; ++n)
                sacc[n] = __builtin_amdgcn_mfma_f32_16x16x32_bf16(aq[kk], kf[kk * 4 + n], sacc[n], 0, 0, 0);

        // ---- prefetch next-iter K fragments (land during softmax + PV) ----
        if (it < qt) {
            const int k1 = k0 + 64;
#pragma unroll
            for (int kk = 0; kk < 4; ++kk)
#pragma unroll
                for (int n = 0; n < 4; ++n)
                    kf[kk * 4 + n] = *(const bf16x8*)(kbase + (size_t)(k1 + n * 16 + l15) * PH + kk * 32 + quad * 8);
        }

        // ---- scale + causal mask (diagonal tile only) ----
        float sraw[4][4];
        const bool diag = (k0 == q0);
#pragma unroll
        for (int n = 0; n < 4; ++n)
#pragma unroll
            for (int r = 0; r < 4; ++r) {
                float s = sacc[n][r] * ATT_SCALE;
                if (diag) {
                    int kg = n * 16 + l15;
                    int qg = wave * 16 + quad * 4 + r;
                    if (kg > qg) s = -1e30f;
                }
                sraw[n][r] = s;
            }

        // ---- online softmax, register-resident ----
        float mx[4];
#pragma unroll
        for (int r = 0; r < 4; ++r)
            mx[r] = fmaxf(fmaxf(sraw[0][r], sraw[1][r]), fmaxf(sraw[2][r], sraw[3][r]));
#pragma unroll
        for (int sh = 1; sh < 16; sh <<= 1)
#pragma unroll
            for (int r = 0; r < 4; ++r)
                mx[r] = fmaxf(mx[r], __shfl_xor(mx[r], sh, 64));

        float alpha[4];
#pragma unroll
        for (int r = 0; r < 4; ++r) {
            float mn = fmaxf(m_prev[r], mx[r]);
            alpha[r] = __expf(m_prev[r] - mn);
            m_prev[r] = mn;
        }

        float rs[4] = {0, 0, 0, 0};
#pragma unroll
        for (int n = 0; n < 4; ++n)
#pragma unroll
            for (int r = 0; r < 4; ++r) {
                float p = __expf(sraw[n][r] - m_prev[r]);
                rs[r] += p;
                Ps[wave][quad * 4 + r][n * 16 + l15] = f2bf(p);  // wave-private: no barrier
            }
#pragma unroll
        for (int sh = 1; sh < 16; sh <<= 1)
#pragma unroll
            for (int r = 0; r < 4; ++r)
                rs[r] += __shfl_xor(rs[r], sh, 64);
#pragma unroll
        for (int r = 0; r < 4; ++r)
            l_run[r] = l_run[r] * alpha[r] + rs[r];

        // ---- rescale O, then O += P V from register V fragments ----
#pragma unroll
        for (int n = 0; n < 8; ++n)
#pragma unroll
            for (int r = 0; r < 4; ++r)
                oacc[n][r] *= alpha[r];

#pragma unroll
        for (int kk = 0; kk < 2; ++kk) {
            bf16x8 ap = *(const bf16x8*)&Ps[wave][l15][kk * 32 + quad * 8];
#pragma unroll
            for (int n = 0; n < 8; ++n)
                oacc[n] = __builtin_amdgcn_mfma_f32_16x16x32_bf16(ap, vf[kk * 8 + n], oacc[n], 0, 0, 0);
        }
    }

    // ---- epilogue: normalize, store bf16 ----
    float inv[4];
#pragma unroll
    for (int r = 0; r < 4; ++r) inv[r] = 1.0f / l_run[r];
#pragma unroll
    for (int n = 0; n < 8; ++n)
#pragma unroll
        for (int r = 0; r < 4; ++r) {
            int row = q0 + wave * 16 + quad * 4 + r;
            int col = h * PHD + n * 16 + l15;
            o[(size_t)(b * PS + row) * PH + col] = f2bf(oacc[n][r] * inv[r]);
        }
}

// ---------------- host launcher ----------------
extern "C" void kernel_launch(void* const* d_in, const int* in_sizes, int n_in,
                              void* d_out, int out_size, void* d_ws, size_t ws_size,
                              hipStream_t stream)
{
    const float* x      = (const float*)d_in[0];
    const float* wq     = (const float*)d_in[1];
    const float* bq     = (const float*)d_in[2];
    const float* wk_lat = (const float*)d_in[3];
    const float* wv_lat = (const float*)d_in[4];
    const float* wk     = (const float*)d_in[5];
    const float* wv     = (const float*)d_in[6];
    const float* wo     = (const float*)d_in[7];
    const float* bo     = (const float*)d_in[8];
    float* out = (float*)d_out;

    char* ws = (char*)d_ws;
    size_t off = 0;
    auto alloc = [&](size_t bytes) -> void* {
        void* p = ws + off;
        off += (bytes + 255) & ~(size_t)255;
        return p;
    };
    unsigned short* xb      = (unsigned short*)alloc((size_t)PM * PH * 2);
    unsigned short* wqT     = (unsigned short*)alloc((size_t)PH * PH * 2);
    unsigned short* wkLatT  = (unsigned short*)alloc((size_t)PLD * PH * 2);
    unsigned short* wvLatT  = (unsigned short*)alloc((size_t)PLD * PH * 2);
    unsigned short* wkT     = (unsigned short*)alloc((size_t)PH * PLD * 2);
    unsigned short* wvT     = (unsigned short*)alloc((size_t)PH * PLD * 2);
    unsigned short* woT     = (unsigned short*)alloc((size_t)PH * PH * 2);
    unsigned short* qb      = (unsigned short*)alloc((size_t)PM * PH * 2);
    unsigned short* klat    = (unsigned short*)alloc((size_t)PM * PLD * 2);
    unsigned short* vlat    = (unsigned short*)alloc((size_t)PM * PLD * 2);
    unsigned short* kb      = (unsigned short*)alloc((size_t)PM * PH * 2);
    unsigned short* vb      = (unsigned short*)alloc((size_t)PM * PH * 2);
    unsigned short* attn    = (unsigned short*)alloc((size_t)PM * PH * 2);
    // vt aliases xb: xb dead after the three GEMMs reading it; vt built after them.
    unsigned short* vt      = xb;

    dim3 tb(32, 8);

    // 1. cast x -> bf16
    cast_f32_bf16_kernel<<<(PM * PH) / 4 / 256, 256, 0, stream>>>(x, xb, PM * PH);
    // 2. transpose weights -> bf16 B^T layouts
    transpose_cast_kernel<<<dim3(PH / 32,  PH / 32),  tb, 0, stream>>>(wq,     wqT,    PH,  PH);
    transpose_cast_kernel<<<dim3(PLD / 32, PH / 32),  tb, 0, stream>>>(wk_lat, wkLatT, PH,  PLD);
    transpose_cast_kernel<<<dim3(PLD / 32, PH / 32),  tb, 0, stream>>>(wv_lat, wvLatT, PH,  PLD);
    transpose_cast_kernel<<<dim3(PH / 32,  PLD / 32), tb, 0, stream>>>(wk,     wkT,    PLD, PH);
    transpose_cast_kernel<<<dim3(PH / 32,  PLD / 32), tb, 0, stream>>>(wv,     wvT,    PLD, PH);
    transpose_cast_kernel<<<dim3(PH / 32,  PH / 32),  tb, 0, stream>>>(wo,     woT,    PH,  PH);

    // 3. projections (128-tile for N>=2048, 64-tile for N=512)
    gemm_bt128_kernel<true, true ><<<dim3(PH / 128,  PM / 128), 256, 0, stream>>>(xb,   wqT,    bq,      qb,   PM, PH,  PH);
    gemm_bt_kernel   <true, false><<<dim3(PLD / 64,  PM / 64),  256, 0, stream>>>(xb,   wkLatT, nullptr, klat, PM, PLD, PH);
    gemm_bt_kernel   <true, false><<<dim3(PLD / 64,  PM / 64),  256, 0, stream>>>(xb,   wvLatT, nullptr, vlat, PM, PLD, PH);
    gemm_bt128_kernel<true, false><<<dim3(PH / 128,  PM / 128), 256, 0, stream>>>(klat, wkT,    nullptr, kb,   PM, PH,  PLD);
    gemm_bt128_kernel<true, false><<<dim3(PH / 128,  PM / 128), 256, 0, stream>>>(vlat, wvT,    nullptr, vb,   PM, PH,  PLD);

    // 3b. V -> V^T per head (PV B-fragments read [dim][key] contiguous)
    transpose_v_kernel<<<dim3(PS / 32, PHD / 32, PB * PNH), tb, 0, stream>>>(vb, vt);

    // 4. causal MFMA flash attention (barrier-free, register-pipelined)
    flash_attn_mfma_kernel<<<PB * PNH * (PS / 64), 256, 0, stream>>>(qb, kb, vt, attn);

    // 5. output projection (fp32 out + bias)
    gemm_bt128_kernel<false, true><<<dim3(PH / 128, PM / 128), 256, 0, stream>>>(attn, woT, bo, out, PM, PH, PH);
}

// Round 5
// 445.857 us; speedup vs baseline: 4.3706x; 1.3474x over previous
//
#include <hip/hip_runtime.h>
#include <hip/hip_bf16.h>

// ---------------- constants (problem shape) ----------------
// B=2, S=2048, H=2048, NH=16, LD=512, HD=128
#define PB   2
#define PS   2048
#define PH   2048
#define PNH  16
#define PLD  512
#define PHD  128
#define PM   (PB * PS)          // 4096 rows in all GEMMs
#define ATT_SCALE 0.08838834764831845f  // 1/sqrt(128)

typedef __attribute__((ext_vector_type(8))) short bf16x8;
typedef __attribute__((ext_vector_type(4))) float f32x4;

__device__ __forceinline__ float bf2f(unsigned int h) {
    return __uint_as_float(h << 16);
}
__device__ __forceinline__ unsigned short f2bf(float f) {
    unsigned int u = __float_as_uint(f);
    u += 0x7FFFu + ((u >> 16) & 1u);   // RNE
    return (unsigned short)(u >> 16);
}

// async global->LDS, 16 B per lane; LDS dest = wave-uniform base + lane*16
__device__ __forceinline__ void gl_lds16(const unsigned short* g, unsigned short* l) {
    __builtin_amdgcn_global_load_lds(
        (const __attribute__((address_space(1))) unsigned int*)g,
        (__attribute__((address_space(3))) unsigned int*)l, 16, 0, 0);
}

// ---------------- cast fp32 -> bf16 (elementwise, 4/thread) ----------------
__global__ __launch_bounds__(256) void cast_f32_bf16_kernel(
    const float* __restrict__ in, unsigned short* __restrict__ out, int n)
{
    int i = (blockIdx.x * 256 + threadIdx.x) * 4;
    if (i >= n) return;
    float4 f = *(const float4*)(in + i);
    unsigned int a = (unsigned int)f2bf(f.x) | ((unsigned int)f2bf(f.y) << 16);
    unsigned int b = (unsigned int)f2bf(f.z) | ((unsigned int)f2bf(f.w) << 16);
    *(uint2*)(out + i) = make_uint2(a, b);
}

// ---------------- transpose + cast: in fp32 [R][C] -> out bf16 [C][R] ----------------
__global__ __launch_bounds__(256) void transpose_cast_kernel(
    const float* __restrict__ in, unsigned short* __restrict__ out, int R, int C)
{
    __shared__ float tile[32][33];
    int tx = threadIdx.x, ty = threadIdx.y;
    int r0 = blockIdx.y * 32, c0 = blockIdx.x * 32;
#pragma unroll
    for (int i = 0; i < 32; i += 8)
        tile[ty + i][tx] = in[(size_t)(r0 + ty + i) * C + (c0 + tx)];
    __syncthreads();
#pragma unroll
    for (int i = 0; i < 32; i += 8)
        out[(size_t)(c0 + ty + i) * R + (r0 + tx)] = f2bf(tile[tx][ty + i]);
}

// ---------------- repack V: vb [B][S][H] -> vswz per head, per 64-key tile:
// [key-chunk c(8)][dim r(128)][8 keys]  (PV B-fragment order, linear staging)
__global__ __launch_bounds__(256) void repack_v_kernel(
    const unsigned short* __restrict__ vb, unsigned short* __restrict__ vswz)
{
    __shared__ unsigned short tile[64][33];
    const int t0 = blockIdx.x * 64;       // key base (tile-aligned)
    const int d0 = blockIdx.y * 32;       // dim base
    const int bh = blockIdx.z;            // 0..31 = b*16+h
    const int b = bh >> 4, h = bh & 15;
    const int tx = threadIdx.x & 31, ty = threadIdx.x >> 5;  // 32 x 8
#pragma unroll
    for (int i = 0; i < 8; ++i)
        tile[ty + i * 8][tx] = vb[(size_t)(b * PS + t0 + ty + i * 8) * PH + h * PHD + d0 + tx];
    __syncthreads();
    unsigned short tmp[8];
#pragma unroll
    for (int j = 0; j < 8; ++j) tmp[j] = tile[ty * 8 + j][tx];
    size_t idx = ((size_t)bh << 18) + ((size_t)(t0 >> 6) << 13) + (ty << 10) + ((size_t)(d0 + tx) << 3);
    *(uint4*)&vswz[idx] = *(const uint4*)tmp;   // 16B store, lane-coalesced
}

// ---------------- 64-tile bf16 MFMA GEMM (N=512 GEMMs) ----------------
template<bool BF16_OUT, bool HAS_BIAS>
__global__ __launch_bounds__(256) void gemm_bt_kernel(
    const unsigned short* __restrict__ A,
    const unsigned short* __restrict__ BT,
    const float* __restrict__ bias,
    void* __restrict__ Cout,
    int M, int N, int K)
{
    __shared__ __align__(16) unsigned short As[64 * 32];
    __shared__ __align__(16) unsigned short Bs[64 * 32];

    const int tid  = threadIdx.x;
    const int wave = tid >> 6;
    const int lane = tid & 63;
    const int wm = wave >> 1, wn = wave & 1;
    const int quad = lane >> 4, l15 = lane & 15;
    const int bm = blockIdx.y * 64, bn = blockIdx.x * 64;

    f32x4 acc[2][2] = {};

    const int lr = tid >> 2;
    const int lc = (tid & 3) * 8;
    const unsigned short* aptr = A  + (size_t)(bm + lr) * K + lc;
    const unsigned short* bptr = BT + (size_t)(bn + lr) * K + lc;
    unsigned short* aL = &As[wave * 16 * 32];
    unsigned short* bL = &Bs[wave * 16 * 32];

    for (int k0 = 0; k0 < K; k0 += 32) {
        gl_lds16(aptr + k0, aL);
        gl_lds16(bptr + k0, bL);
        __syncthreads();
        bf16x8 a0 = *(const bf16x8*)&As[(wm * 32 +      l15) * 32 + quad * 8];
        bf16x8 a1 = *(const bf16x8*)&As[(wm * 32 + 16 + l15) * 32 + quad * 8];
        bf16x8 b0 = *(const bf16x8*)&Bs[(wn * 32 +      l15) * 32 + quad * 8];
        bf16x8 b1 = *(const bf16x8*)&Bs[(wn * 32 + 16 + l15) * 32 + quad * 8];
        acc[0][0] = __builtin_amdgcn_mfma_f32_16x16x32_bf16(a0, b0, acc[0][0], 0, 0, 0);
        acc[0][1] = __builtin_amdgcn_mfma_f32_16x16x32_bf16(a0, b1, acc[0][1], 0, 0, 0);
        acc[1][0] = __builtin_amdgcn_mfma_f32_16x16x32_bf16(a1, b0, acc[1][0], 0, 0, 0);
        acc[1][1] = __builtin_amdgcn_mfma_f32_16x16x32_bf16(a1, b1, acc[1][1], 0, 0, 0);
        __syncthreads();
    }

#pragma unroll
    for (int mi = 0; mi < 2; ++mi)
#pragma unroll
        for (int ni = 0; ni < 2; ++ni)
#pragma unroll
            for (int r = 0; r < 4; ++r) {
                int row = bm + wm * 32 + mi * 16 + quad * 4 + r;
                int col = bn + wn * 32 + ni * 16 + l15;
                float val = acc[mi][ni][r];
                if (HAS_BIAS) val += bias[col];
                if (BF16_OUT)
                    ((unsigned short*)Cout)[(size_t)row * N + col] = f2bf(val);
                else
                    ((float*)Cout)[(size_t)row * N + col] = val;
            }
}

// ---------------- 128-tile bf16 MFMA GEMM (m97 structure) ----------------
// KSWZ: write output in K-fragment-swizzled layout (per head, per 64-key tile).
template<bool BF16_OUT, bool HAS_BIAS, bool KSWZ>
__global__ __launch_bounds__(256) void gemm_bt128_kernel(
    const unsigned short* __restrict__ A,
    const unsigned short* __restrict__ BT,
    const float* __restrict__ bias,
    void* __restrict__ Cout,
    int M, int N, int K)
{
    __shared__ __align__(16) unsigned short As[128 * 32];
    __shared__ __align__(16) unsigned short Bs[128 * 32];

    const int tid  = threadIdx.x;
    const int wave = tid >> 6;
    const int lane = tid & 63;
    const int wm = wave >> 1, wn = wave & 1;
    const int quad = lane >> 4, l15 = lane & 15;
    const int bm = blockIdx.y * 128, bn = blockIdx.x * 128;

    f32x4 acc[4][4] = {};

    const int srow = wave * 32 + (lane >> 2);
    const int scol = (lane & 3) * 8;
    const unsigned short* aG = A  + (size_t)(bm + srow) * K + scol;
    const unsigned short* bG = BT + (size_t)(bn + srow) * K + scol;
    unsigned short* aL = &As[wave * 32 * 32];
    unsigned short* bL = &Bs[wave * 32 * 32];

    for (int k0 = 0; k0 < K; k0 += 32) {
        gl_lds16(aG + k0,                    aL);
        gl_lds16(aG + k0 + (size_t)16 * K,   aL + 16 * 32);
        gl_lds16(bG + k0,                    bL);
        gl_lds16(bG + k0 + (size_t)16 * K,   bL + 16 * 32);
        __syncthreads();
        bf16x8 af[4], bfr[4];
#pragma unroll
        for (int i = 0; i < 4; ++i) {
            af[i]  = *(const bf16x8*)&As[(wm * 64 + i * 16 + l15) * 32 + quad * 8];
            bfr[i] = *(const bf16x8*)&Bs[(wn * 64 + i * 16 + l15) * 32 + quad * 8];
        }
#pragma unroll
        for (int i = 0; i < 4; ++i)
#pragma unroll
            for (int j = 0; j < 4; ++j)
                acc[i][j] = __builtin_amdgcn_mfma_f32_16x16x32_bf16(af[i], bfr[j], acc[i][j], 0, 0, 0);
        __syncthreads();
    }

#pragma unroll
    for (int i = 0; i < 4; ++i)
#pragma unroll
        for (int j = 0; j < 4; ++j)
#pragma unroll
            for (int r = 0; r < 4; ++r) {
                int row = bm + wm * 64 + i * 16 + quad * 4 + r;
                int col = bn + wn * 64 + j * 16 + l15;
                float val = acc[i][j][r];
                if (HAS_BIAS) val += bias[col];
                if (KSWZ) {
                    // K fragment layout: head (b*16+h): [tile s/64][dim-chunk d/8][key s%64][d%8]
                    int bb = row >> 11, s = row & 2047, hh = col >> 7, d = col & 127;
                    size_t idx = ((size_t)((bb << 4) + hh) << 18) + ((size_t)(s >> 6) << 13)
                               + ((d >> 3) << 9) + ((s & 63) << 3) + (d & 7);
                    ((unsigned short*)Cout)[idx] = f2bf(val);
                } else if (BF16_OUT) {
                    ((unsigned short*)Cout)[(size_t)row * N + col] = f2bf(val);
                } else {
                    ((float*)Cout)[(size_t)row * N + col] = val;
                }
            }
}

// ---------------- MFMA flash attention, LDS-staged, swizzled K/V ----------------
// grid 1024 blocks, 256 threads (4 waves x 16 queries = 64-query tile).
// kswz/vswz are in MFMA-fragment order: staging = linear gl_lds16 copy (coalesced),
// LDS frag reads are per-quad-contiguous (2-way bank alias = free).
__global__ __launch_bounds__(256) void flash_attn_mfma_kernel(
    const unsigned short* __restrict__ q,
    const unsigned short* __restrict__ kswz,
    const unsigned short* __restrict__ vswz,
    unsigned short* __restrict__ o)
{
    __shared__ __align__(16) unsigned short Kl[8192];       // 16KB: [chunk(16)][key(64)][8]
    __shared__ __align__(16) unsigned short Vl[8192];       // 16KB: [chunk(8)][dim(128)][8]
    __shared__ __align__(16) unsigned short Ps[4][16][72];  // wave-private P

    const int tid  = threadIdx.x;
    const int wave = tid >> 6;
    const int lane = tid & 63;
    const int quad = lane >> 4, l15 = lane & 15;

    const int bid = blockIdx.x;
    const int qt = 31 - (bid >> 5);     // longest tiles dispatch first
    const int bh = bid & 31;            // head pinned to one XCD-L2 (bid%8 const per head)
    const int b  = bh >> 4, h = bh & 15;
    const int q0 = qt * 64;

    const unsigned short* qbase = q + (size_t)(b * PS + q0) * PH + h * PHD;
    const unsigned short* kbase = kswz + ((size_t)bh << 18);
    const unsigned short* vbase = vswz + ((size_t)bh << 18);

    // Q A-frags: registers for whole kernel (one-time scattered read, negligible)
    bf16x8 aq[4];
#pragma unroll
    for (int kk = 0; kk < 4; ++kk)
        aq[kk] = *(const bf16x8*)(qbase + (size_t)(wave * 16 + l15) * PH + kk * 32 + quad * 8);

    f32x4 oacc[8] = {};
    float m_prev[4], l_run[4];
#pragma unroll
    for (int r = 0; r < 4; ++r) { m_prev[r] = -1e30f; l_run[r] = 0.0f; }

    for (int it = 0; it <= qt; ++it) {
        const unsigned short* kt = kbase + (size_t)it * 8192;
        const unsigned short* vt = vbase + (size_t)it * 8192;
        __syncthreads();   // prior-iter frag readers done before re-staging
#pragma unroll
        for (int j = 0; j < 4; ++j) {
            gl_lds16(kt + (wave * 4 + j) * 512 + lane * 8, &Kl[(wave * 4 + j) * 512]);
            gl_lds16(vt + (wave * 4 + j) * 512 + lane * 8, &Vl[(wave * 4 + j) * 512]);
        }
        __syncthreads();   // staging complete

        // ---- S = Q K^T ----
        f32x4 sacc[4] = {};
#pragma unroll
        for (int kk = 0; kk < 4; ++kk)
#pragma unroll
            for (int n = 0; n < 4; ++n) {
                bf16x8 bk = *(const bf16x8*)&Kl[((kk * 4 + quad) * 64 + n * 16 + l15) * 8];
                sacc[n] = __builtin_amdgcn_mfma_f32_16x16x32_bf16(aq[kk], bk, sacc[n], 0, 0, 0);
            }

        // ---- scale + causal mask (diagonal tile only) ----
        float sraw[4][4];
        const bool diag = (it == qt);
#pragma unroll
        for (int n = 0; n < 4; ++n)
#pragma unroll
            for (int r = 0; r < 4; ++r) {
                float s = sacc[n][r] * ATT_SCALE;
                if (diag) {
                    int kg = n * 16 + l15;
                    int qg = wave * 16 + quad * 4 + r;
                    if (kg > qg) s = -1e30f;
                }
                sraw[n][r] = s;
            }

        // ---- online softmax, register-resident ----
        float mx[4];
#pragma unroll
        for (int r = 0; r < 4; ++r)
            mx[r] = fmaxf(fmaxf(sraw[0][r], sraw[1][r]), fmaxf(sraw[2][r], sraw[3][r]));
#pragma unroll
        for (int sh = 1; sh < 16; sh <<= 1)
#pragma unroll
            for (int r = 0; r < 4; ++r)
                mx[r] = fmaxf(mx[r], __shfl_xor(mx[r], sh, 64));

        float alpha[4];
#pragma unroll
        for (int r = 0; r < 4; ++r) {
            float mn = fmaxf(m_prev[r], mx[r]);
            alpha[r] = __expf(m_prev[r] - mn);
            m_prev[r] = mn;
        }

        float rs[4] = {0, 0, 0, 0};
#pragma unroll
        for (int n = 0; n < 4; ++n)
#pragma unroll
            for (int r = 0; r < 4; ++r) {
                float p = __expf(sraw[n][r] - m_prev[r]);
                rs[r] += p;
                Ps[wave][quad * 4 + r][n * 16 + l15] = f2bf(p);  // wave-private: no barrier
            }
#pragma unroll
        for (int sh = 1; sh < 16; sh <<= 1)
#pragma unroll
            for (int r = 0; r < 4; ++r)
                rs[r] += __shfl_xor(rs[r], sh, 64);
#pragma unroll
        for (int r = 0; r < 4; ++r)
            l_run[r] = l_run[r] * alpha[r] + rs[r];

        // ---- rescale O, then O += P V ----
#pragma unroll
        for (int n = 0; n < 8; ++n)
#pragma unroll
            for (int r = 0; r < 4; ++r)
                oacc[n][r] *= alpha[r];

#pragma unroll
        for (int kk = 0; kk < 2; ++kk) {
            bf16x8 ap = *(const bf16x8*)&Ps[wave][l15][kk * 32 + quad * 8];
#pragma unroll
            for (int n = 0; n < 8; ++n) {
                bf16x8 bv = *(const bf16x8*)&Vl[((kk * 4 + quad) * 128 + n * 16 + l15) * 8];
                oacc[n] = __builtin_amdgcn_mfma_f32_16x16x32_bf16(ap, bv, oacc[n], 0, 0, 0);
            }
        }
    }

    // ---- epilogue: normalize, store bf16 ----
    float inv[4];
#pragma unroll
    for (int r = 0; r < 4; ++r) inv[r] = 1.0f / l_run[r];
#pragma unroll
    for (int n = 0; n < 8; ++n)
#pragma unroll
        for (int r = 0; r < 4; ++r) {
            int row = q0 + wave * 16 + quad * 4 + r;
            int col = h * PHD + n * 16 + l15;
            o[(size_t)(b * PS + row) * PH + col] = f2bf(oacc[n][r] * inv[r]);
        }
}

// ---------------- host launcher ----------------
extern "C" void kernel_launch(void* const* d_in, const int* in_sizes, int n_in,
                              void* d_out, int out_size, void* d_ws, size_t ws_size,
                              hipStream_t stream)
{
    const float* x      = (const float*)d_in[0];
    const float* wq     = (const float*)d_in[1];
    const float* bq     = (const float*)d_in[2];
    const float* wk_lat = (const float*)d_in[3];
    const float* wv_lat = (const float*)d_in[4];
    const float* wk     = (const float*)d_in[5];
    const float* wv     = (const float*)d_in[6];
    const float* wo     = (const float*)d_in[7];
    const float* bo     = (const float*)d_in[8];
    float* out = (float*)d_out;

    char* ws = (char*)d_ws;
    size_t off = 0;
    auto alloc = [&](size_t bytes) -> void* {
        void* p = ws + off;
        off += (bytes + 255) & ~(size_t)255;
        return p;
    };
    unsigned short* xb      = (unsigned short*)alloc((size_t)PM * PH * 2);
    unsigned short* wqT     = (unsigned short*)alloc((size_t)PH * PH * 2);
    unsigned short* wkLatT  = (unsigned short*)alloc((size_t)PLD * PH * 2);
    unsigned short* wvLatT  = (unsigned short*)alloc((size_t)PLD * PH * 2);
    unsigned short* wkT     = (unsigned short*)alloc((size_t)PH * PLD * 2);
    unsigned short* wvT     = (unsigned short*)alloc((size_t)PH * PLD * 2);
    unsigned short* woT     = (unsigned short*)alloc((size_t)PH * PH * 2);
    unsigned short* qb      = (unsigned short*)alloc((size_t)PM * PH * 2);
    unsigned short* klat    = (unsigned short*)alloc((size_t)PM * PLD * 2);
    unsigned short* vlat    = (unsigned short*)alloc((size_t)PM * PLD * 2);
    unsigned short* kswz    = (unsigned short*)alloc((size_t)PM * PH * 2);
    unsigned short* vb      = (unsigned short*)alloc((size_t)PM * PH * 2);
    unsigned short* attn    = (unsigned short*)alloc((size_t)PM * PH * 2);
    // vswz aliases xb: xb dead after the three GEMMs reading it; vswz built after them.
    unsigned short* vswz    = xb;

    dim3 tb(32, 8);

    // 1. cast x -> bf16
    cast_f32_bf16_kernel<<<(PM * PH) / 4 / 256, 256, 0, stream>>>(x, xb, PM * PH);
    // 2. transpose weights -> bf16 B^T layouts
    transpose_cast_kernel<<<dim3(PH / 32,  PH / 32),  tb, 0, stream>>>(wq,     wqT,    PH,  PH);
    transpose_cast_kernel<<<dim3(PLD / 32, PH / 32),  tb, 0, stream>>>(wk_lat, wkLatT, PH,  PLD);
    transpose_cast_kernel<<<dim3(PLD / 32, PH / 32),  tb, 0, stream>>>(wv_lat, wvLatT, PH,  PLD);
    transpose_cast_kernel<<<dim3(PH / 32,  PLD / 32), tb, 0, stream>>>(wk,     wkT,    PLD, PH);
    transpose_cast_kernel<<<dim3(PH / 32,  PLD / 32), tb, 0, stream>>>(wv,     wvT,    PLD, PH);
    transpose_cast_kernel<<<dim3(PH / 32,  PH / 32),  tb, 0, stream>>>(wo,     woT,    PH,  PH);

    // 3. projections
    gemm_bt128_kernel<true, true,  false><<<dim3(PH / 128,  PM / 128), 256, 0, stream>>>(xb,   wqT,    bq,      qb,   PM, PH,  PH);
    gemm_bt_kernel   <true, false       ><<<dim3(PLD / 64,  PM / 64),  256, 0, stream>>>(xb,   wkLatT, nullptr, klat, PM, PLD, PH);
    gemm_bt_kernel   <true, false       ><<<dim3(PLD / 64,  PM / 64),  256, 0, stream>>>(xb,   wvLatT, nullptr, vlat, PM, PLD, PH);
    gemm_bt128_kernel<true, false, true ><<<dim3(PH / 128,  PM / 128), 256, 0, stream>>>(klat, wkT,    nullptr, kswz, PM, PH,  PLD);
    gemm_bt128_kernel<true, false, false><<<dim3(PH / 128,  PM / 128), 256, 0, stream>>>(vlat, wvT,    nullptr, vb,   PM, PH,  PLD);

    // 3b. V -> fragment-swizzled V^T per head
    repack_v_kernel<<<dim3(PS / 64, PHD / 32, PB * PNH), 256, 0, stream>>>(vb, vswz);

    // 4. causal MFMA flash attention (LDS-staged, coalesced)
    flash_attn_mfma_kernel<<<PB * PNH * (PS / 64), 256, 0, stream>>>(qb, kswz, vswz, attn);

    // 5. output projection (fp32 out + bias)
    gemm_bt128_kernel<false, true, false><<<dim3(PH / 128, PM / 128), 256, 0, stream>>>(attn, woT, bo, out, PM, PH, PH);
}

// Round 6
// 409.548 us; speedup vs baseline: 4.7581x; 1.0887x over previous
//
#include <hip/hip_runtime.h>
#include <hip/hip_bf16.h>

// ---------------- constants (problem shape) ----------------
// B=2, S=2048, H=2048, NH=16, LD=512, HD=128
#define PB   2
#define PS   2048
#define PH   2048
#define PNH  16
#define PLD  512
#define PHD  128
#define PM   (PB * PS)          // 4096 rows in all GEMMs
#define PNCAT 3072              // merged down-proj width: 2048 q + 512 klat + 512 vlat
#define ATT_SCALE 0.08838834764831845f  // 1/sqrt(128)

typedef __attribute__((ext_vector_type(8))) short bf16x8;
typedef __attribute__((ext_vector_type(4))) float f32x4;

__device__ __forceinline__ float bf2f(unsigned int h) {
    return __uint_as_float(h << 16);
}
__device__ __forceinline__ unsigned short f2bf(float f) {
    unsigned int u = __float_as_uint(f);
    u += 0x7FFFu + ((u >> 16) & 1u);   // RNE
    return (unsigned short)(u >> 16);
}

// async global->LDS, 16 B per lane; LDS dest = wave-uniform base + lane*16
__device__ __forceinline__ void gl_lds16(const unsigned short* g, unsigned short* l) {
    __builtin_amdgcn_global_load_lds(
        (const __attribute__((address_space(1))) unsigned int*)g,
        (__attribute__((address_space(3))) unsigned int*)l, 16, 0, 0);
}

// ---------------- cast fp32 -> bf16 (elementwise, 4/thread) ----------------
__global__ __launch_bounds__(256) void cast_f32_bf16_kernel(
    const float* __restrict__ in, unsigned short* __restrict__ out, int n)
{
    int i = (blockIdx.x * 256 + threadIdx.x) * 4;
    if (i >= n) return;
    float4 f = *(const float4*)(in + i);
    unsigned int a = (unsigned int)f2bf(f.x) | ((unsigned int)f2bf(f.y) << 16);
    unsigned int b = (unsigned int)f2bf(f.z) | ((unsigned int)f2bf(f.w) << 16);
    *(uint2*)(out + i) = make_uint2(a, b);
}

// ---------------- transpose + cast: in fp32 [R][C] -> out bf16 [C][R] ----------------
__global__ __launch_bounds__(256) void transpose_cast_kernel(
    const float* __restrict__ in, unsigned short* __restrict__ out, int R, int C)
{
    __shared__ float tile[32][33];
    int tx = threadIdx.x, ty = threadIdx.y;
    int r0 = blockIdx.y * 32, c0 = blockIdx.x * 32;
#pragma unroll
    for (int i = 0; i < 32; i += 8)
        tile[ty + i][tx] = in[(size_t)(r0 + ty + i) * C + (c0 + tx)];
    __syncthreads();
#pragma unroll
    for (int i = 0; i < 32; i += 8)
        out[(size_t)(c0 + ty + i) * R + (r0 + tx)] = f2bf(tile[tx][ty + i]);
}

// ---------------- 128-tile bf16 MFMA GEMM, strided, multi-epilogue ----------------
// EPI: 0 = bf16 row-major, 1 = fp32 row-major, 2 = K-swizzled, 3 = V-swizzled.
// A [M][*] stride lda; BT [N][K] stride K. grid (N/128, M/128), 256 threads.
template<int EPI, bool HAS_BIAS>
__global__ __launch_bounds__(256) void gemm128_kernel(
    const unsigned short* __restrict__ A, int lda,
    const unsigned short* __restrict__ BT,
    const float* __restrict__ bias, int nbias,
    void* __restrict__ Cout, int ldc,
    int M, int N, int K)
{
    __shared__ __align__(16) unsigned short As[128 * 32];
    __shared__ __align__(16) unsigned short Bs[128 * 32];

    const int tid  = threadIdx.x;
    const int wave = tid >> 6;
    const int lane = tid & 63;
    const int wm = wave >> 1, wn = wave & 1;
    const int quad = lane >> 4, l15 = lane & 15;
    const int bm = blockIdx.y * 128, bn = blockIdx.x * 128;

    f32x4 acc[4][4] = {};

    const int srow = wave * 32 + (lane >> 2);
    const int scol = (lane & 3) * 8;
    const unsigned short* aG = A  + (size_t)(bm + srow) * lda + scol;
    const unsigned short* bG = BT + (size_t)(bn + srow) * K + scol;
    unsigned short* aL = &As[wave * 32 * 32];
    unsigned short* bL = &Bs[wave * 32 * 32];

    for (int k0 = 0; k0 < K; k0 += 32) {
        gl_lds16(aG + k0,                    aL);
        gl_lds16(aG + k0 + (size_t)16 * lda, aL + 16 * 32);
        gl_lds16(bG + k0,                    bL);
        gl_lds16(bG + k0 + (size_t)16 * K,   bL + 16 * 32);
        __syncthreads();
        bf16x8 af[4], bfr[4];
#pragma unroll
        for (int i = 0; i < 4; ++i) {
            af[i]  = *(const bf16x8*)&As[(wm * 64 + i * 16 + l15) * 32 + quad * 8];
            bfr[i] = *(const bf16x8*)&Bs[(wn * 64 + i * 16 + l15) * 32 + quad * 8];
        }
#pragma unroll
        for (int i = 0; i < 4; ++i)
#pragma unroll
            for (int j = 0; j < 4; ++j)
                acc[i][j] = __builtin_amdgcn_mfma_f32_16x16x32_bf16(af[i], bfr[j], acc[i][j], 0, 0, 0);
        __syncthreads();
    }

#pragma unroll
    for (int i = 0; i < 4; ++i)
#pragma unroll
        for (int j = 0; j < 4; ++j)
#pragma unroll
            for (int r = 0; r < 4; ++r) {
                int row = bm + wm * 64 + i * 16 + quad * 4 + r;
                int col = bn + wn * 64 + j * 16 + l15;
                float val = acc[i][j][r];
                if (HAS_BIAS && col < nbias) val += bias[col];
                if (EPI == 2) {
                    // K frag layout, head bh=b*16+h: [tile s/64][dim-chunk d/8][key s%64][d%8]
                    int bb = row >> 11, s = row & 2047, hh = col >> 7, d = col & 127;
                    size_t idx = ((size_t)((bb << 4) + hh) << 18) + ((size_t)(s >> 6) << 13)
                               + ((d >> 3) << 9) + ((s & 63) << 3) + (d & 7);
                    ((unsigned short*)Cout)[idx] = f2bf(val);
                } else if (EPI == 3) {
                    // V frag layout, head bh: [tile s/64][key-chunk (s%64)/8][dim d(128)][s%8]
                    int bb = row >> 11, s = row & 2047, hh = col >> 7, d = col & 127;
                    size_t idx = ((size_t)((bb << 4) + hh) << 18) + ((size_t)(s >> 6) << 13)
                               + (((s >> 3) & 7) << 10) + (d << 3) + (s & 7);
                    ((unsigned short*)Cout)[idx] = f2bf(val);
                } else if (EPI == 1) {
                    ((float*)Cout)[(size_t)row * ldc + col] = val;
                } else {
                    ((unsigned short*)Cout)[(size_t)row * ldc + col] = f2bf(val);
                }
            }
}

// ---------------- MFMA flash attention, LDS-staged, K-dbuf prefetch ----------------
// grid 1024 blocks, 256 threads (4 waves x 16 queries = 64-query tile).
// K double-buffered (prefetched 1 iter ahead); V staged at iter top, consumed
// after softmax (barrier B2). Every gl_lds16 has >=1 compute phase in flight
// before the barrier that drains it. Q rows have stride PNCAT (merged buffer).
__global__ __launch_bounds__(256) void flash_attn_mfma_kernel(
    const unsigned short* __restrict__ q,
    const unsigned short* __restrict__ kswz,
    const unsigned short* __restrict__ vswz,
    unsigned short* __restrict__ o)
{
    __shared__ __align__(16) unsigned short Kl[2][8192];    // 32 KB dbuf
    __shared__ __align__(16) unsigned short Vl[8192];       // 16 KB
    __shared__ __align__(16) unsigned short Ps[4][16][72];  // wave-private P

    const int tid  = threadIdx.x;
    const int wave = tid >> 6;
    const int lane = tid & 63;
    const int quad = lane >> 4, l15 = lane & 15;

    const int bid = blockIdx.x;
    const int qt = 31 - (bid >> 5);     // longest tiles dispatch first
    const int bh = bid & 31;            // head pinned to one XCD-L2
    const int b  = bh >> 4, h = bh & 15;
    const int q0 = qt * 64;

    const unsigned short* qbase = q + (size_t)(b * PS + q0) * PNCAT + h * PHD;
    const unsigned short* kbase = kswz + ((size_t)bh << 18);
    const unsigned short* vbase = vswz + ((size_t)bh << 18);

    auto stageK = [&](int it, int buf) {
        const unsigned short* kt = kbase + ((size_t)it << 13);
#pragma unroll
        for (int j = 0; j < 4; ++j)
            gl_lds16(kt + (wave * 4 + j) * 512 + lane * 8, &Kl[buf][(wave * 4 + j) * 512]);
    };
    auto stageV = [&](int it) {
        const unsigned short* vt = vbase + ((size_t)it << 13);
#pragma unroll
        for (int j = 0; j < 4; ++j)
            gl_lds16(vt + (wave * 4 + j) * 512 + lane * 8, &Vl[(wave * 4 + j) * 512]);
    };

    // Q A-frags: registers for whole kernel
    bf16x8 aq[4];
#pragma unroll
    for (int kk = 0; kk < 4; ++kk)
        aq[kk] = *(const bf16x8*)(qbase + (size_t)(wave * 16 + l15) * PNCAT + kk * 32 + quad * 8);

    f32x4 oacc[8] = {};
    float m_prev[4], l_run[4];
#pragma unroll
    for (int r = 0; r < 4; ++r) { m_prev[r] = -1e30f; l_run[r] = 0.0f; }

    stageK(0, 0);   // prologue prefetch

    for (int it = 0; it <= qt; ++it) {
        const int cur = it & 1;
        __syncthreads();   // B1: K[it] visible everywhere; V[it-1]/Ps readers done
        stageV(it);
        if (it < qt) stageK(it + 1, cur ^ 1);

        // ---- S = Q K^T on Kl[cur] ----
        f32x4 sacc[4] = {};
#pragma unroll
        for (int kk = 0; kk < 4; ++kk)
#pragma unroll
            for (int n = 0; n < 4; ++n) {
                bf16x8 bk = *(const bf16x8*)&Kl[cur][((kk * 4 + quad) * 64 + n * 16 + l15) * 8];
                sacc[n] = __builtin_amdgcn_mfma_f32_16x16x32_bf16(aq[kk], bk, sacc[n], 0, 0, 0);
            }

        // ---- scale + causal mask (diagonal tile only) ----
        float sraw[4][4];
        const bool diag = (it == qt);
#pragma unroll
        for (int n = 0; n < 4; ++n)
#pragma unroll
            for (int r = 0; r < 4; ++r) {
                float s = sacc[n][r] * ATT_SCALE;
                if (diag) {
                    int kg = n * 16 + l15;
                    int qg = wave * 16 + quad * 4 + r;
                    if (kg > qg) s = -1e30f;
                }
                sraw[n][r] = s;
            }

        // ---- online softmax, register-resident ----
        float mx[4];
#pragma unroll
        for (int r = 0; r < 4; ++r)
            mx[r] = fmaxf(fmaxf(sraw[0][r], sraw[1][r]), fmaxf(sraw[2][r], sraw[3][r]));
#pragma unroll
        for (int sh = 1; sh < 16; sh <<= 1)
#pragma unroll
            for (int r = 0; r < 4; ++r)
                mx[r] = fmaxf(mx[r], __shfl_xor(mx[r], sh, 64));

        float alpha[4];
#pragma unroll
        for (int r = 0; r < 4; ++r) {
            float mn = fmaxf(m_prev[r], mx[r]);
            alpha[r] = __expf(m_prev[r] - mn);
            m_prev[r] = mn;
        }

        float rs[4] = {0, 0, 0, 0};
#pragma unroll
        for (int n = 0; n < 4; ++n)
#pragma unroll
            for (int r = 0; r < 4; ++r) {
                float p = __expf(sraw[n][r] - m_prev[r]);
                rs[r] += p;
                Ps[wave][quad * 4 + r][n * 16 + l15] = f2bf(p);  // wave-private
            }
#pragma unroll
        for (int sh = 1; sh < 16; sh <<= 1)
#pragma unroll
            for (int r = 0; r < 4; ++r)
                rs[r] += __shfl_xor(rs[r], sh, 64);
#pragma unroll
        for (int r = 0; r < 4; ++r)
            l_run[r] = l_run[r] * alpha[r] + rs[r];

        // ---- rescale O (independent of V; fills B2 wait) ----
#pragma unroll
        for (int n = 0; n < 8; ++n)
#pragma unroll
            for (int r = 0; r < 4; ++r)
                oacc[n][r] *= alpha[r];

        __syncthreads();   // B2: V[it] visible (loads had QK+softmax in flight)

        // ---- O += P V ----
#pragma unroll
        for (int kk = 0; kk < 2; ++kk) {
            bf16x8 ap = *(const bf16x8*)&Ps[wave][l15][kk * 32 + quad * 8];
#pragma unroll
            for (int n = 0; n < 8; ++n) {
                bf16x8 bv = *(const bf16x8*)&Vl[((kk * 4 + quad) * 128 + n * 16 + l15) * 8];
                oacc[n] = __builtin_amdgcn_mfma_f32_16x16x32_bf16(ap, bv, oacc[n], 0, 0, 0);
            }
        }
    }

    // ---- epilogue: normalize, store bf16 ----
    float inv[4];
#pragma unroll
    for (int r = 0; r < 4; ++r) inv[r] = 1.0f / l_run[r];
#pragma unroll
    for (int n = 0; n < 8; ++n)
#pragma unroll
        for (int r = 0; r < 4; ++r) {
            int row = q0 + wave * 16 + quad * 4 + r;
            int col = h * PHD + n * 16 + l15;
            o[(size_t)(b * PS + row) * PH + col] = f2bf(oacc[n][r] * inv[r]);
        }
}

// ---------------- host launcher ----------------
extern "C" void kernel_launch(void* const* d_in, const int* in_sizes, int n_in,
                              void* d_out, int out_size, void* d_ws, size_t ws_size,
                              hipStream_t stream)
{
    const float* x      = (const float*)d_in[0];
    const float* wq     = (const float*)d_in[1];
    const float* bq     = (const float*)d_in[2];
    const float* wk_lat = (const float*)d_in[3];
    const float* wv_lat = (const float*)d_in[4];
    const float* wk     = (const float*)d_in[5];
    const float* wv     = (const float*)d_in[6];
    const float* wo     = (const float*)d_in[7];
    const float* bo     = (const float*)d_in[8];
    float* out = (float*)d_out;

    char* ws = (char*)d_ws;
    size_t off = 0;
    auto alloc = [&](size_t bytes) -> void* {
        void* p = ws + off;
        off += (bytes + 255) & ~(size_t)255;
        return p;
    };
    unsigned short* xb    = (unsigned short*)alloc((size_t)PM * PH * 2);       // 16 MB
    unsigned short* wcatT = (unsigned short*)alloc((size_t)PNCAT * PH * 2);    // 12 MB: [wqT | wkLatT | wvLatT]
    unsigned short* wkT   = (unsigned short*)alloc((size_t)PH * PLD * 2);      // 2 MB
    unsigned short* wvT   = (unsigned short*)alloc((size_t)PH * PLD * 2);      // 2 MB
    unsigned short* woT   = (unsigned short*)alloc((size_t)PH * PH * 2);       // 8 MB
    unsigned short* cat   = (unsigned short*)alloc((size_t)PM * PNCAT * 2);    // 24 MB: [q | klat | vlat]
    unsigned short* kswz  = (unsigned short*)alloc((size_t)PM * PH * 2);       // 16 MB
    unsigned short* attn  = (unsigned short*)alloc((size_t)PM * PH * 2);       // 16 MB
    // vswz aliases xb: xb dead after the merged down-proj reads it.
    unsigned short* vswz  = xb;

    unsigned short* wqT    = wcatT;                                  // rows 0..2047
    unsigned short* wkLatT = wcatT + (size_t)PH * PH;                // rows 2048..2559
    unsigned short* wvLatT = wcatT + (size_t)(PH + PLD) * PH;        // rows 2560..3071

    dim3 tb(32, 8);

    // 1. cast x -> bf16
    cast_f32_bf16_kernel<<<(PM * PH) / 4 / 256, 256, 0, stream>>>(x, xb, PM * PH);
    // 2. transpose weights -> bf16 B^T layouts (down-proj weights into one buffer)
    transpose_cast_kernel<<<dim3(PH / 32,  PH / 32),  tb, 0, stream>>>(wq,     wqT,    PH,  PH);
    transpose_cast_kernel<<<dim3(PLD / 32, PH / 32),  tb, 0, stream>>>(wk_lat, wkLatT, PH,  PLD);
    transpose_cast_kernel<<<dim3(PLD / 32, PH / 32),  tb, 0, stream>>>(wv_lat, wvLatT, PH,  PLD);
    transpose_cast_kernel<<<dim3(PH / 32,  PLD / 32), tb, 0, stream>>>(wk,     wkT,    PLD, PH);
    transpose_cast_kernel<<<dim3(PH / 32,  PLD / 32), tb, 0, stream>>>(wv,     wvT,    PLD, PH);
    transpose_cast_kernel<<<dim3(PH / 32,  PH / 32),  tb, 0, stream>>>(wo,     woT,    PH,  PH);

    // 3. merged down-projection: cat[M][3072] = xb @ [wq | wk_lat | wv_lat] (+bq on first 2048 cols)
    gemm128_kernel<0, true><<<dim3(PNCAT / 128, PM / 128), 256, 0, stream>>>(
        xb, PH, wcatT, bq, PH, cat, PNCAT, PM, PNCAT, PH);

    // 4. up-projections straight into MFMA-fragment-swizzled K / V
    gemm128_kernel<2, false><<<dim3(PH / 128, PM / 128), 256, 0, stream>>>(
        cat + PH, PNCAT, wkT, nullptr, 0, kswz, 0, PM, PH, PLD);
    gemm128_kernel<3, false><<<dim3(PH / 128, PM / 128), 256, 0, stream>>>(
        cat + PH + PLD, PNCAT, wvT, nullptr, 0, vswz, 0, PM, PH, PLD);

    // 5. causal MFMA flash attention (K-dbuf prefetch, Q from cat with stride 3072)
    flash_attn_mfma_kernel<<<PB * PNH * (PS / 64), 256, 0, stream>>>(cat, kswz, vswz, attn);

    // 6. output projection (fp32 out + bo)
    gemm128_kernel<1, true><<<dim3(PH / 128, PM / 128), 256, 0, stream>>>(
        attn, PH, woT, bo, PH, out, PH, PM, PH, PH);
}